// Round 2
// baseline (266.648 us; speedup 1.0000x reference)
//
#include <hip/hip_runtime.h>
#include <math.h>

#define D 256
#define NH 8
#define HD 32
#define EDIM 64

// ---------------------------------------------------------------- LayerNorm
__global__ __launch_bounds__(256) void ln_kernel(const float* __restrict__ x,
    const float* __restrict__ g, const float* __restrict__ b,
    float* __restrict__ out) {
  int row = blockIdx.x;
  int tid = threadIdx.x;               // 256 threads == D
  float v = x[row * D + tid];
  float s = v, sq = v * v;
  #pragma unroll
  for (int m = 1; m < 64; m <<= 1) { s += __shfl_xor(s, m); sq += __shfl_xor(sq, m); }
  __shared__ float ps[4], pq[4];
  int wid = tid >> 6, lane = tid & 63;
  if (lane == 0) { ps[wid] = s; pq[wid] = sq; }
  __syncthreads();
  float ts = ps[0] + ps[1] + ps[2] + ps[3];
  float tq = pq[0] + pq[1] + pq[2] + pq[3];
  float mu  = ts * (1.f / D);
  float var = tq * (1.f / D) - mu * mu;
  float inv = 1.f / sqrtf(var + 1e-5f);
  out[row * D + tid] = (v - mu) * inv * g[tid] + b[tid];
}

// ---------------------------------------------------------------- SGEMM core
// 64x64 tile, BK=32, 256 threads, 4x4 microtile.
__device__ __forceinline__ void gemm_mainloop(const float* __restrict__ A,
    const float* __restrict__ W, int lda, int Nn, int bm, int bn,
    int k_begin, int k_end, int tid, float (*As)[64], float (*Bs)[64],
    float acc[4][4]) {
  int tx = tid & 15, ty = tid >> 4;          // 16x16 threads
  int am = tid >> 2, ak = (tid & 3) * 4;     // A-tile load coords
  for (int k0 = k_begin; k0 < k_end; k0 += 32) {
    float4 a0 = *(const float4*)(A + (size_t)(bm + am) * lda + k0 + ak);
    float4 a1 = *(const float4*)(A + (size_t)(bm + am) * lda + k0 + ak + 16);
    float4 b0 = *(const float4*)(W + (size_t)(k0 + ty) * Nn + bn + tx * 4);
    float4 b1 = *(const float4*)(W + (size_t)(k0 + ty + 16) * Nn + bn + tx * 4);
    As[ak +  0][am] = a0.x; As[ak +  1][am] = a0.y; As[ak +  2][am] = a0.z; As[ak +  3][am] = a0.w;
    As[ak + 16][am] = a1.x; As[ak + 17][am] = a1.y; As[ak + 18][am] = a1.z; As[ak + 19][am] = a1.w;
    *(float4*)&Bs[ty][tx * 4]      = b0;
    *(float4*)&Bs[ty + 16][tx * 4] = b1;
    __syncthreads();
    #pragma unroll
    for (int kk = 0; kk < 32; kk++) {
      float4 av = *(const float4*)&As[kk][ty * 4];
      float4 bv = *(const float4*)&Bs[kk][tx * 4];
      float ar[4] = {av.x, av.y, av.z, av.w};
      float br[4] = {bv.x, bv.y, bv.z, bv.w};
      #pragma unroll
      for (int i = 0; i < 4; i++)
        #pragma unroll
        for (int j = 0; j < 4; j++) acc[i][j] = fmaf(ar[i], br[j], acc[i][j]);
    }
    __syncthreads();
  }
}

// C[z] = A @ W[z] + bias[z].  EPI: 0 = bias, 1 = bias + exact gelu
template <int EPI>
__global__ __launch_bounds__(256) void gemm_kernel(
    const float* __restrict__ A,
    const float* __restrict__ W0p, const float* __restrict__ W1p, const float* __restrict__ W2p,
    const float* __restrict__ b0p, const float* __restrict__ b1p, const float* __restrict__ b2p,
    float* __restrict__ C0p, float* __restrict__ C1p, float* __restrict__ C2p,
    int M, int Nn, int K) {
  int z = blockIdx.z;
  const float* W    = (z == 0) ? W0p : (z == 1) ? W1p : W2p;
  const float* bias = (z == 0) ? b0p : (z == 1) ? b1p : b2p;
  float* C          = (z == 0) ? C0p : (z == 1) ? C1p : C2p;
  __shared__ __align__(16) float As[32][64];
  __shared__ __align__(16) float Bs[32][64];
  int tid = threadIdx.x;
  int bm = blockIdx.y * 64, bn = blockIdx.x * 64;
  float acc[4][4] = {};
  gemm_mainloop(A, W, K, Nn, bm, bn, 0, K, tid, As, Bs, acc);
  int tx = tid & 15, ty = tid >> 4;
  #pragma unroll
  for (int i = 0; i < 4; i++) {
    int row = bm + ty * 4 + i;
    #pragma unroll
    for (int j = 0; j < 4; j++) {
      int colx = bn + tx * 4 + j;
      float v = acc[i][j] + bias[colx];
      if constexpr (EPI == 1) v = 0.5f * v * (1.f + erff(v * 0.70710678118654752f));
      C[(size_t)row * Nn + colx] = v;
    }
  }
}

// split-K partial:  P[z] = A @ W over K-slice z (no bias)
__global__ __launch_bounds__(256) void gemm_splitk_kernel(
    const float* __restrict__ A, const float* __restrict__ W,
    float* __restrict__ P, int M, int Nn, int K, int Kslice) {
  int z = blockIdx.z;
  __shared__ __align__(16) float As[32][64];
  __shared__ __align__(16) float Bs[32][64];
  int tid = threadIdx.x;
  int bm = blockIdx.y * 64, bn = blockIdx.x * 64;
  float acc[4][4] = {};
  gemm_mainloop(A, W, K, Nn, bm, bn, z * Kslice, (z + 1) * Kslice, tid, As, Bs, acc);
  float* Pz = P + (size_t)z * M * Nn;
  int tx = tid & 15, ty = tid >> 4;
  #pragma unroll
  for (int i = 0; i < 4; i++) {
    int row = bm + ty * 4 + i;
    #pragma unroll
    for (int j = 0; j < 4; j++)
      Pz[(size_t)row * Nn + bn + tx * 4 + j] = acc[i][j];
  }
}

// out = sum_s P[s] + bias + R   (float4 grid-stride)
__global__ __launch_bounds__(256) void reduce_kernel(const float* __restrict__ P,
    const float* __restrict__ bias, const float* __restrict__ R,
    float* __restrict__ out, int MN, int Nn, int S) {
  int i = blockIdx.x * 256 + threadIdx.x;     // float4 index
  if (i * 4 >= MN) return;
  size_t b = (size_t)i * 4;
  float4 acc = *(const float4*)(P + b);
  for (int s = 1; s < S; s++) {
    float4 p = *(const float4*)(P + (size_t)s * MN + b);
    acc.x += p.x; acc.y += p.y; acc.z += p.z; acc.w += p.w;
  }
  float4 bi = *(const float4*)(bias + (b % Nn));
  float4 r  = *(const float4*)(R + b);
  acc.x += bi.x + r.x; acc.y += bi.y + r.y; acc.z += bi.z + r.z; acc.w += bi.w + r.w;
  *(float4*)(out + b) = acc;
}

// ---------------------------------------------------------------- edge bias: eb[e,h] = edge_attr[e,:] @ We[:,h] + be[h]
__global__ __launch_bounds__(256) void edge_bias_kernel(const float* __restrict__ ea,
    const float* __restrict__ We, const float* __restrict__ be,
    float* __restrict__ eb, int E) {
  int e = blockIdx.x * 256 + threadIdx.x;
  if (e >= E) return;
  const float* row = ea + (size_t)e * EDIM;
  float acc[NH];
  #pragma unroll
  for (int h = 0; h < NH; h++) acc[h] = be[h];
  #pragma unroll 4
  for (int k = 0; k < EDIM; k++) {
    float r = row[k];                       // per-lane row; L1/L2 absorb
    #pragma unroll
    for (int h = 0; h < NH; h++) acc[h] = fmaf(r, We[k * NH + h], acc[h]);  // uniform -> s_load
  }
  #pragma unroll
  for (int h = 0; h < NH; h++) eb[e * NH + h] = acc[h];
}

// ---------------------------------------------------------------- duplicate-edge winner (.set semantics: last edge wins)
__global__ void winner_kernel(const int* __restrict__ ei, int* __restrict__ Wn, int E, int N) {
  int e = blockIdx.x * 256 + threadIdx.x;
  if (e >= E) return;
  int s = ei[e], d = ei[E + e];
  atomicMax(&Wn[(size_t)s * N + d], e);
}
__global__ void count_kernel(const int* __restrict__ ei, const int* __restrict__ Wn,
                             int* __restrict__ cnt, int E, int N) {
  int e = blockIdx.x * 256 + threadIdx.x;
  if (e >= E) return;
  int s = ei[e], d = ei[E + e];
  if (Wn[(size_t)s * N + d] == e) atomicAdd(&cnt[s], 1);
}
__global__ void self_count_kernel(const int* __restrict__ Wn, int* __restrict__ cnt, int N) {
  int n = blockIdx.x * 256 + threadIdx.x;
  if (n >= N) return;
  if (Wn[(size_t)n * N + n] == -1) cnt[n] += 1;   // unique thread per n, separate launch: no race
}

// ---------------------------------------------------------------- exclusive scan over cnt[N] -> rowptr[N+1], cursor[N]
__global__ __launch_bounds__(256) void scan_kernel(const int* __restrict__ cnt,
    int* __restrict__ rowptr, int* __restrict__ cursor, int N) {
  __shared__ int part[256];
  int tid = threadIdx.x;
  int chunk = (N + 255) / 256;
  int base = tid * chunk;
  int s = 0;
  for (int i = 0; i < chunk; i++) { int idx = base + i; if (idx < N) s += cnt[idx]; }
  part[tid] = s;
  __syncthreads();
  for (int off = 1; off < 256; off <<= 1) {
    int v = (tid >= off) ? part[tid - off] : 0;
    __syncthreads();
    part[tid] += v;
    __syncthreads();
  }
  int run = (tid == 0) ? 0 : part[tid - 1];
  for (int i = 0; i < chunk; i++) {
    int idx = base + i;
    if (idx < N) { rowptr[idx] = run; cursor[idx] = run; run += cnt[idx]; }
  }
  if (tid == 255) rowptr[N] = part[255];
}

__global__ void scatter_kernel(const int* __restrict__ ei, const int* __restrict__ Wn,
    int* __restrict__ cursor, int* __restrict__ col, int* __restrict__ bidx, int E, int N) {
  int e = blockIdx.x * 256 + threadIdx.x;
  if (e >= E) return;
  int s = ei[e], d = ei[E + e];
  if (Wn[(size_t)s * N + d] == e) {
    int p = atomicAdd(&cursor[s], 1);
    col[p] = d; bidx[p] = e;
  }
}
__global__ void self_scatter_kernel(const int* __restrict__ Wn, const int* __restrict__ cursor,
    int* __restrict__ col, int* __restrict__ bidx, int N) {
  int n = blockIdx.x * 256 + threadIdx.x;
  if (n >= N) return;
  if (Wn[(size_t)n * N + n] == -1) {
    int p = cursor[n];                // next free slot (self counted but not yet placed)
    col[p] = n; bidx[p] = -1;         // bias 0 for implicit self-loop
  }
}

// ---------------------------------------------------------------- sparse attention, online softmax
// one wave per row n; lane = h*8 + j; lane owns dims [j*4, j*4+4) of head h
__global__ __launch_bounds__(256) void attn_kernel(const float* __restrict__ Q,
    const float* __restrict__ Km, const float* __restrict__ Vm,
    const float* __restrict__ eb, const int* __restrict__ rowptr,
    const int* __restrict__ col, const int* __restrict__ bidx,
    float* __restrict__ out, int N) {
  int wid = threadIdx.x >> 6, lane = threadIdx.x & 63;
  int n = blockIdx.x * 4 + wid;
  if (n >= N) return;
  int h = lane >> 3, j = lane & 7;
  int off = h * HD + j * 4;
  float4 q = *(const float4*)(Q + (size_t)n * D + off);
  float mrun = -INFINITY, srun = 0.f;
  float4 acc = make_float4(0.f, 0.f, 0.f, 0.f);
  int beg = rowptr[n], end = rowptr[n + 1];
  for (int i = beg; i < end; i++) {
    int m = col[i];
    int be_ = bidx[i];
    float4 k4 = *(const float4*)(Km + (size_t)m * D + off);
    float dot = q.x * k4.x + q.y * k4.y + q.z * k4.z + q.w * k4.w;
    dot += __shfl_xor(dot, 1); dot += __shfl_xor(dot, 2); dot += __shfl_xor(dot, 4);
    float bias = (be_ >= 0) ? eb[be_ * NH + h] : 0.f;
    float sc = fmaf(dot, 0.17677669529663687f, bias);   // / sqrt(32)
    float mnew = fmaxf(mrun, sc);
    float corr = __expf(mrun - mnew);                   // first iter: exp(-inf)=0
    float p = __expf(sc - mnew);
    float4 v4 = *(const float4*)(Vm + (size_t)m * D + off);
    srun = srun * corr + p;
    acc.x = fmaf(acc.x, corr, p * v4.x);
    acc.y = fmaf(acc.y, corr, p * v4.y);
    acc.z = fmaf(acc.z, corr, p * v4.z);
    acc.w = fmaf(acc.w, corr, p * v4.w);
    mrun = mnew;
  }
  float inv = 1.f / srun;
  float4 o = make_float4(acc.x * inv, acc.y * inv, acc.z * inv, acc.w * inv);
  *(float4*)(out + (size_t)n * D + off) = o;
}

// ----------------------------------------------------------------
extern "C" void kernel_launch(void* const* d_in, const int* in_sizes, int n_in,
                              void* d_out, int out_size, void* d_ws, size_t ws_size,
                              hipStream_t stream) {
  const float* x    = (const float*)d_in[0];
  const int*   ei   = (const int*)d_in[1];
  const float* ea   = (const float*)d_in[2];
  const float* Wq   = (const float*)d_in[3];  const float* bq = (const float*)d_in[4];
  const float* Wk   = (const float*)d_in[5];  const float* bk = (const float*)d_in[6];
  const float* Wv   = (const float*)d_in[7];  const float* bv = (const float*)d_in[8];
  const float* Wo   = (const float*)d_in[9];  const float* bo = (const float*)d_in[10];
  const float* We   = (const float*)d_in[11]; const float* be = (const float*)d_in[12];
  const float* W1   = (const float*)d_in[13]; const float* b1 = (const float*)d_in[14];
  const float* W2   = (const float*)d_in[15]; const float* b2 = (const float*)d_in[16];
  const float* ln1g = (const float*)d_in[17]; const float* ln1b = (const float*)d_in[18];
  const float* ln2g = (const float*)d_in[19]; const float* ln2b = (const float*)d_in[20];

  int N = in_sizes[0] / D;
  int E = in_sizes[1] / 2;

  char* p = (char*)d_ws;
  auto alloc = [&](size_t bytes) -> char* {
    char* r = p; p += (bytes + 255) & ~(size_t)255; return r;
  };
  int*   Wn     = (int*)  alloc((size_t)N * N * 4);
  float* h      = (float*)alloc((size_t)N * D * 4);
  float* Qd     = (float*)alloc((size_t)N * D * 4);
  float* Kd     = (float*)alloc((size_t)N * D * 4);
  float* Vd     = (float*)alloc((size_t)N * D * 4);
  float* attn_o = (float*)alloc((size_t)N * D * 4);
  float* x_mid  = (float*)alloc((size_t)N * D * 4);
  float* ebuf   = (float*)alloc((size_t)E * NH * 4);
  float* t      = (float*)alloc((size_t)N * 4 * D * 4);
  float* P      = (float*)alloc((size_t)4 * N * D * 4);   // split-K partials (max S=4)
  int*   cnt    = (int*)  alloc((size_t)N * 4);
  int*   rowptr = (int*)  alloc((size_t)(N + 1) * 4);
  int*   cursor = (int*)  alloc((size_t)N * 4);
  int*   colA   = (int*)  alloc((size_t)(E + N) * 4);
  int*   bidxA  = (int*)  alloc((size_t)(E + N) * 4);

  hipMemsetAsync(Wn, 0xFF, (size_t)N * N * 4, stream);   // -1
  hipMemsetAsync(cnt, 0, (size_t)N * 4, stream);

  int MN = N * D;

  // LN1 + QKV
  ln_kernel<<<N, 256, 0, stream>>>(x, ln1g, ln1b, h);
  dim3 g_qkv(D / 64, N / 64, 3);
  gemm_kernel<0><<<g_qkv, 256, 0, stream>>>(h, Wq, Wk, Wv, bq, bk, bv, Qd, Kd, Vd,
                                            N, D, D);
  // edge bias + CSR with .set-winner dedupe
  edge_bias_kernel<<<(E + 255) / 256, 256, 0, stream>>>(ea, We, be, ebuf, E);
  winner_kernel<<<(E + 255) / 256, 256, 0, stream>>>(ei, Wn, E, N);
  count_kernel<<<(E + 255) / 256, 256, 0, stream>>>(ei, Wn, cnt, E, N);
  self_count_kernel<<<(N + 255) / 256, 256, 0, stream>>>(Wn, cnt, N);
  scan_kernel<<<1, 256, 0, stream>>>(cnt, rowptr, cursor, N);
  scatter_kernel<<<(E + 255) / 256, 256, 0, stream>>>(ei, Wn, cursor, colA, bidxA, E, N);
  self_scatter_kernel<<<(N + 255) / 256, 256, 0, stream>>>(Wn, cursor, colA, bidxA, N);
  // attention
  attn_kernel<<<(N + 3) / 4, 256, 0, stream>>>(Qd, Kd, Vd, ebuf, rowptr, colA, bidxA,
                                               attn_o, N);
  // output proj (split-K=2) + bias + residual -> x_mid
  {
    dim3 g(D / 64, N / 64, 2);
    gemm_splitk_kernel<<<g, 256, 0, stream>>>(attn_o, Wo, P, N, D, D, D / 2);
    reduce_kernel<<<(MN / 4 + 255) / 256, 256, 0, stream>>>(P, bo, x, x_mid, MN, D, 2);
  }
  // LN2 + FFN
  ln_kernel<<<N, 256, 0, stream>>>(x_mid, ln2g, ln2b, h);   // h reused as h2
  dim3 g_1(4 * D / 64, N / 64, 1);
  gemm_kernel<1><<<g_1, 256, 0, stream>>>(h, W1, W1, W1, b1, b1, b1, t, t, t,
                                          N, 4 * D, D);
  // W2 (split-K=4) + bias + residual -> d_out
  {
    dim3 g(D / 64, N / 64, 4);
    gemm_splitk_kernel<<<g, 256, 0, stream>>>(t, W2, P, N, D, 4 * D, D);
    reduce_kernel<<<(MN / 4 + 255) / 256, 256, 0, stream>>>(P, b2, x_mid, (float*)d_out,
                                                            MN, D, 4);
  }
}

// Round 4
// 231.490 us; speedup vs baseline: 1.1519x; 1.1519x over previous
//
#include <hip/hip_runtime.h>
#include <math.h>

#define D 256
#define NH 8
#define HD 32
#define EDIM 64

typedef __attribute__((ext_vector_type(8))) short bfrag;   // 8 bf16 (4 VGPRs)
typedef __attribute__((ext_vector_type(4))) float ffrag;   // 4 fp32 acc

__device__ __forceinline__ unsigned short f2bf(float x) {  // RNE fp32->bf16
  unsigned int u = __float_as_uint(x);
  return (unsigned short)((u + 0x7FFFu + ((u >> 16) & 1u)) >> 16);
}

// ---------------------------------------------------------------- LayerNorm -> bf16
__global__ __launch_bounds__(256) void ln_kernel(const float* __restrict__ x,
    const float* __restrict__ g, const float* __restrict__ b,
    unsigned short* __restrict__ out) {
  int row = blockIdx.x;
  int tid = threadIdx.x;               // 256 threads == D
  float v = x[row * D + tid];
  float s = v, sq = v * v;
  #pragma unroll
  for (int m = 1; m < 64; m <<= 1) { s += __shfl_xor(s, m); sq += __shfl_xor(sq, m); }
  __shared__ float ps[4], pq[4];
  int wid = tid >> 6, lane = tid & 63;
  if (lane == 0) { ps[wid] = s; pq[wid] = sq; }
  __syncthreads();
  float ts = ps[0] + ps[1] + ps[2] + ps[3];
  float tq = pq[0] + pq[1] + pq[2] + pq[3];
  float mu  = ts * (1.f / D);
  float var = tq * (1.f / D) - mu * mu;
  float inv = 1.f / sqrtf(var + 1e-5f);
  out[row * D + tid] = f2bf((v - mu) * inv * g[tid] + b[tid]);
}

// ---------------------------------------------------------------- weight cast fp32->bf16
// regions: Wq,Wk,Wv,Wo (65536 each), W1 (262144), W2 (262144)
__global__ __launch_bounds__(256) void cast6_kernel(
    const float* __restrict__ s0, const float* __restrict__ s1,
    const float* __restrict__ s2, const float* __restrict__ s3,
    const float* __restrict__ s4, const float* __restrict__ s5,
    unsigned short* __restrict__ d0, unsigned short* __restrict__ d1,
    unsigned short* __restrict__ d2, unsigned short* __restrict__ d3,
    unsigned short* __restrict__ d4, unsigned short* __restrict__ d5) {
  int i = (blockIdx.x * 256 + threadIdx.x) * 4;
  const float* s; unsigned short* d; int off;
  if      (i < 65536)  { s = s0; d = d0; off = i; }
  else if (i < 131072) { s = s1; d = d1; off = i - 65536; }
  else if (i < 196608) { s = s2; d = d2; off = i - 131072; }
  else if (i < 262144) { s = s3; d = d3; off = i - 196608; }
  else if (i < 524288) { s = s4; d = d4; off = i - 262144; }
  else if (i < 786432) { s = s5; d = d5; off = i - 524288; }
  else return;
  float4 v = *(const float4*)(s + off);
  ushort4 o = make_ushort4(f2bf(v.x), f2bf(v.y), f2bf(v.z), f2bf(v.w));
  *(ushort4*)(d + off) = o;
}

// ---------------------------------------------------------------- bf16 MFMA GEMM core
// A:[M,K] bf16 row-major, B:[K,Nn] bf16 row-major. 64x64 tile, BK=32,
// 256 threads = 4 waves; wave w owns rows [w*16, w*16+16).
// LDS: As[64][40], Bt[64][40] (B staged TRANSPOSED: Bt[n][k]); row pitch 80 B.
// Frag layouts (HW-verified, learn_hip m89/m91):
//   A: row=lane&15, k=(lane>>4)*8+j  -> As[row][k]
//   B: col=lane&15, k=(lane>>4)*8+j  -> Bt[col][k]
//   C: col=lane&15, row=(lane>>4)*4+reg
__device__ __forceinline__ void mg_core(const unsigned short* __restrict__ A,
    const unsigned short* __restrict__ B, int K, int Nn, int bm, int bn,
    int kb0, int kb1, unsigned short (*As)[40], unsigned short (*Bt)[40],
    ffrag acc[4]) {
  int tid = threadIdx.x;
  int wid = tid >> 6, lane = tid & 63;
  int lr = lane & 15, lk = lane >> 4;        // frag row/col, k-group
  int ar = tid >> 2, ak = (tid & 3) * 8;     // A staging: row, k-offset (8 bf16)
  int bnn = tid & 63, bkg = tid >> 6;        // B staging: col n, k-group of 8
  for (int kb = kb0; kb < kb1; kb += 32) {
    uint4 av = *(const uint4*)(A + (size_t)(bm + ar) * K + kb + ak);
    *(uint4*)&As[ar][ak] = av;
    unsigned int u[4];
    #pragma unroll
    for (int jj = 0; jj < 4; jj++) {
      unsigned short lo = B[(size_t)(kb + bkg * 8 + 2 * jj)     * Nn + bn + bnn];
      unsigned short hi = B[(size_t)(kb + bkg * 8 + 2 * jj + 1) * Nn + bn + bnn];
      u[jj] = (unsigned int)lo | ((unsigned int)hi << 16);
    }
    *(uint4*)&Bt[bnn][bkg * 8] = make_uint4(u[0], u[1], u[2], u[3]);
    __syncthreads();
    bfrag af = *(const bfrag*)&As[wid * 16 + lr][lk * 8];
    #pragma unroll
    for (int nf = 0; nf < 4; nf++) {
      bfrag bf = *(const bfrag*)&Bt[nf * 16 + lr][lk * 8];
      acc[nf] = __builtin_amdgcn_mfma_f32_16x16x32_bf16(af, bf, acc[nf], 0, 0, 0);
    }
    __syncthreads();
  }
}

// QKV: z selects weight/bias/output. fp32 out = acc + bias.
__global__ __launch_bounds__(256) void mgemm_qkv(const unsigned short* __restrict__ A,
    const unsigned short* __restrict__ B0, const unsigned short* __restrict__ B1,
    const unsigned short* __restrict__ B2,
    const float* __restrict__ b0, const float* __restrict__ b1, const float* __restrict__ b2,
    float* __restrict__ C0, float* __restrict__ C1, float* __restrict__ C2,
    int M, int Nn, int K) {
  __shared__ __align__(16) unsigned short As[64][40];
  __shared__ __align__(16) unsigned short Bt[64][40];
  int z = blockIdx.z;
  const unsigned short* B = (z == 0) ? B0 : (z == 1) ? B1 : B2;
  const float* bias = (z == 0) ? b0 : (z == 1) ? b1 : b2;
  float* C = (z == 0) ? C0 : (z == 1) ? C1 : C2;
  int bm = blockIdx.y * 64, bn = blockIdx.x * 64;
  ffrag acc[4] = {};
  mg_core(A, B, K, Nn, bm, bn, 0, K, As, Bt, acc);
  int lane = threadIdx.x & 63, wid = threadIdx.x >> 6;
  int lr = lane & 15, lk = lane >> 4;
  #pragma unroll
  for (int nf = 0; nf < 4; nf++) {
    int col = bn + nf * 16 + lr;
    float bv = bias[col];
    #pragma unroll
    for (int i = 0; i < 4; i++) {
      int row = bm + wid * 16 + lk * 4 + i;
      C[(size_t)row * Nn + col] = acc[nf][i] + bv;
    }
  }
}

// W1: bf16 out = gelu(acc + bias)
__global__ __launch_bounds__(256) void mgemm_gelu(const unsigned short* __restrict__ A,
    const unsigned short* __restrict__ B, const float* __restrict__ bias,
    unsigned short* __restrict__ C, int M, int Nn, int K) {
  __shared__ __align__(16) unsigned short As[64][40];
  __shared__ __align__(16) unsigned short Bt[64][40];
  int bm = blockIdx.y * 64, bn = blockIdx.x * 64;
  ffrag acc[4] = {};
  mg_core(A, B, K, Nn, bm, bn, 0, K, As, Bt, acc);
  int lane = threadIdx.x & 63, wid = threadIdx.x >> 6;
  int lr = lane & 15, lk = lane >> 4;
  #pragma unroll
  for (int nf = 0; nf < 4; nf++) {
    int col = bn + nf * 16 + lr;
    float bv = bias[col];
    #pragma unroll
    for (int i = 0; i < 4; i++) {
      int row = bm + wid * 16 + lk * 4 + i;
      float v = acc[nf][i] + bv;
      v = 0.5f * v * (1.f + erff(v * 0.70710678118654752f));
      C[(size_t)row * Nn + col] = f2bf(v);
    }
  }
}

// split-K partial: P[z] = A @ B over K-slice z (no bias)
__global__ __launch_bounds__(256) void mgemm_splitk(const unsigned short* __restrict__ A,
    const unsigned short* __restrict__ B, float* __restrict__ P,
    int M, int Nn, int K, int Kslice) {
  __shared__ __align__(16) unsigned short As[64][40];
  __shared__ __align__(16) unsigned short Bt[64][40];
  int z = blockIdx.z;
  int bm = blockIdx.y * 64, bn = blockIdx.x * 64;
  ffrag acc[4] = {};
  mg_core(A, B, K, Nn, bm, bn, z * Kslice, (z + 1) * Kslice, As, Bt, acc);
  float* Pz = P + (size_t)z * M * Nn;
  int lane = threadIdx.x & 63, wid = threadIdx.x >> 6;
  int lr = lane & 15, lk = lane >> 4;
  #pragma unroll
  for (int nf = 0; nf < 4; nf++) {
    int col = bn + nf * 16 + lr;
    #pragma unroll
    for (int i = 0; i < 4; i++) {
      int row = bm + wid * 16 + lk * 4 + i;
      Pz[(size_t)row * Nn + col] = acc[nf][i];
    }
  }
}

// out = sum_s P[s] + bias + R   (float4)
__global__ __launch_bounds__(256) void reduce_kernel(const float* __restrict__ P,
    const float* __restrict__ bias, const float* __restrict__ R,
    float* __restrict__ out, int MN, int Nn, int S) {
  int i = blockIdx.x * 256 + threadIdx.x;
  if (i * 4 >= MN) return;
  size_t b = (size_t)i * 4;
  float4 acc = *(const float4*)(P + b);
  for (int s = 1; s < S; s++) {
    float4 p = *(const float4*)(P + (size_t)s * MN + b);
    acc.x += p.x; acc.y += p.y; acc.z += p.z; acc.w += p.w;
  }
  float4 bi = *(const float4*)(bias + (b % Nn));
  float4 r  = *(const float4*)(R + b);
  acc.x += bi.x + r.x; acc.y += bi.y + r.y; acc.z += bi.z + r.z; acc.w += bi.w + r.w;
  *(float4*)(out + b) = acc;
}

// ---------------------------------------------------------------- edge bias
__global__ __launch_bounds__(256) void edge_bias_kernel(const float* __restrict__ ea,
    const float* __restrict__ We, const float* __restrict__ be,
    float* __restrict__ eb, int E) {
  int e = blockIdx.x * 256 + threadIdx.x;
  if (e >= E) return;
  const float* row = ea + (size_t)e * EDIM;
  float acc[NH];
  #pragma unroll
  for (int h = 0; h < NH; h++) acc[h] = be[h];
  #pragma unroll 4
  for (int k = 0; k < EDIM; k++) {
    float r = row[k];
    #pragma unroll
    for (int h = 0; h < NH; h++) acc[h] = fmaf(r, We[k * NH + h], acc[h]);
  }
  #pragma unroll
  for (int h = 0; h < NH; h++) eb[e * NH + h] = acc[h];
}

// ---------------------------------------------------------------- duplicate-edge winner (.set semantics)
__global__ void winner_kernel(const int* __restrict__ ei, int* __restrict__ Wn, int E, int N) {
  int e = blockIdx.x * 256 + threadIdx.x;
  if (e >= E) return;
  int s = ei[e], d = ei[E + e];
  atomicMax(&Wn[(size_t)s * N + d], e);
}
__global__ void count_kernel(const int* __restrict__ ei, const int* __restrict__ Wn,
                             int* __restrict__ cnt, int E, int N) {
  int e = blockIdx.x * 256 + threadIdx.x;
  if (e >= E) return;
  int s = ei[e], d = ei[E + e];
  if (Wn[(size_t)s * N + d] == e) atomicAdd(&cnt[s], 1);
}
__global__ void self_count_kernel(const int* __restrict__ Wn, int* __restrict__ cnt, int N) {
  int n = blockIdx.x * 256 + threadIdx.x;
  if (n >= N) return;
  if (Wn[(size_t)n * N + n] == -1) cnt[n] += 1;
}

__global__ __launch_bounds__(256) void scan_kernel(const int* __restrict__ cnt,
    int* __restrict__ rowptr, int* __restrict__ cursor, int N) {
  __shared__ int part[256];
  int tid = threadIdx.x;
  int chunk = (N + 255) / 256;
  int base = tid * chunk;
  int s = 0;
  for (int i = 0; i < chunk; i++) { int idx = base + i; if (idx < N) s += cnt[idx]; }
  part[tid] = s;
  __syncthreads();
  for (int off = 1; off < 256; off <<= 1) {
    int v = (tid >= off) ? part[tid - off] : 0;
    __syncthreads();
    part[tid] += v;
    __syncthreads();
  }
  int run = (tid == 0) ? 0 : part[tid - 1];
  for (int i = 0; i < chunk; i++) {
    int idx = base + i;
    if (idx < N) { rowptr[idx] = run; cursor[idx] = run; run += cnt[idx]; }
  }
  if (tid == 255) rowptr[N] = part[255];
}

__global__ void scatter_kernel(const int* __restrict__ ei, const int* __restrict__ Wn,
    int* __restrict__ cursor, int* __restrict__ col, int* __restrict__ bidx, int E, int N) {
  int e = blockIdx.x * 256 + threadIdx.x;
  if (e >= E) return;
  int s = ei[e], d = ei[E + e];
  if (Wn[(size_t)s * N + d] == e) {
    int p = atomicAdd(&cursor[s], 1);
    col[p] = d; bidx[p] = e;
  }
}
__global__ void self_scatter_kernel(const int* __restrict__ Wn, const int* __restrict__ cursor,
    int* __restrict__ col, int* __restrict__ bidx, int N) {
  int n = blockIdx.x * 256 + threadIdx.x;
  if (n >= N) return;
  if (Wn[(size_t)n * N + n] == -1) {
    int p = cursor[n];
    col[p] = n; bidx[p] = -1;
  }
}

// ---------------------------------------------------------------- sparse attention, online softmax -> bf16 out
__global__ __launch_bounds__(256) void attn_kernel(const float* __restrict__ Q,
    const float* __restrict__ Km, const float* __restrict__ Vm,
    const float* __restrict__ eb, const int* __restrict__ rowptr,
    const int* __restrict__ col, const int* __restrict__ bidx,
    unsigned short* __restrict__ out, int N) {
  int wid = threadIdx.x >> 6, lane = threadIdx.x & 63;
  int n = blockIdx.x * 4 + wid;
  if (n >= N) return;
  int h = lane >> 3, j = lane & 7;
  int off = h * HD + j * 4;
  float4 q = *(const float4*)(Q + (size_t)n * D + off);
  float mrun = -INFINITY, srun = 0.f;
  float4 acc = make_float4(0.f, 0.f, 0.f, 0.f);
  int beg = rowptr[n], end = rowptr[n + 1];
  for (int i = beg; i < end; i++) {
    int m = col[i];
    int be_ = bidx[i];
    float4 k4 = *(const float4*)(Km + (size_t)m * D + off);
    float dot = q.x * k4.x + q.y * k4.y + q.z * k4.z + q.w * k4.w;
    dot += __shfl_xor(dot, 1); dot += __shfl_xor(dot, 2); dot += __shfl_xor(dot, 4);
    float bias = (be_ >= 0) ? eb[be_ * NH + h] : 0.f;
    float sc = fmaf(dot, 0.17677669529663687f, bias);
    float mnew = fmaxf(mrun, sc);
    float corr = __expf(mrun - mnew);
    float p = __expf(sc - mnew);
    float4 v4 = *(const float4*)(Vm + (size_t)m * D + off);
    srun = srun * corr + p;
    acc.x = fmaf(acc.x, corr, p * v4.x);
    acc.y = fmaf(acc.y, corr, p * v4.y);
    acc.z = fmaf(acc.z, corr, p * v4.z);
    acc.w = fmaf(acc.w, corr, p * v4.w);
    mrun = mnew;
  }
  float inv = 1.f / srun;
  ushort4 o = make_ushort4(f2bf(acc.x * inv), f2bf(acc.y * inv),
                           f2bf(acc.z * inv), f2bf(acc.w * inv));
  *(ushort4*)(out + (size_t)n * D + off) = o;
}

// ----------------------------------------------------------------
extern "C" void kernel_launch(void* const* d_in, const int* in_sizes, int n_in,
                              void* d_out, int out_size, void* d_ws, size_t ws_size,
                              hipStream_t stream) {
  const float* x    = (const float*)d_in[0];
  const int*   ei   = (const int*)d_in[1];
  const float* ea   = (const float*)d_in[2];
  const float* Wq   = (const float*)d_in[3];  const float* bq = (const float*)d_in[4];
  const float* Wk   = (const float*)d_in[5];  const float* bk = (const float*)d_in[6];
  const float* Wv   = (const float*)d_in[7];  const float* bv = (const float*)d_in[8];
  const float* Wo   = (const float*)d_in[9];  const float* bo = (const float*)d_in[10];
  const float* We   = (const float*)d_in[11]; const float* be = (const float*)d_in[12];
  const float* W1   = (const float*)d_in[13]; const float* b1 = (const float*)d_in[14];
  const float* W2   = (const float*)d_in[15]; const float* b2 = (const float*)d_in[16];
  const float* ln1g = (const float*)d_in[17]; const float* ln1b = (const float*)d_in[18];
  const float* ln2g = (const float*)d_in[19]; const float* ln2b = (const float*)d_in[20];

  int N = in_sizes[0] / D;
  int E = in_sizes[1] / 2;

  char* p = (char*)d_ws;
  auto alloc = [&](size_t bytes) -> char* {
    char* r = p; p += (bytes + 255) & ~(size_t)255; return r;
  };
  int*            Wn     = (int*)           alloc((size_t)N * N * 4);
  unsigned short* hbf    = (unsigned short*)alloc((size_t)N * D * 2);
  float*          Qd     = (float*)         alloc((size_t)N * D * 4);
  float*          Kd     = (float*)         alloc((size_t)N * D * 4);
  float*          Vd     = (float*)         alloc((size_t)N * D * 4);
  unsigned short* attnbf = (unsigned short*)alloc((size_t)N * D * 2);
  float*          x_mid  = (float*)         alloc((size_t)N * D * 4);
  float*          ebuf   = (float*)         alloc((size_t)E * NH * 4);
  unsigned short* tbf    = (unsigned short*)alloc((size_t)N * 4 * D * 2);
  float*          P      = (float*)         alloc((size_t)4 * N * D * 4);
  unsigned short* Wqb    = (unsigned short*)alloc((size_t)D * D * 2);
  unsigned short* Wkb    = (unsigned short*)alloc((size_t)D * D * 2);
  unsigned short* Wvb    = (unsigned short*)alloc((size_t)D * D * 2);
  unsigned short* Wob    = (unsigned short*)alloc((size_t)D * D * 2);
  unsigned short* W1b    = (unsigned short*)alloc((size_t)D * 4 * D * 2);
  unsigned short* W2b    = (unsigned short*)alloc((size_t)4 * D * D * 2);
  int*            cnt    = (int*)           alloc((size_t)N * 4);
  int*            rowptr = (int*)           alloc((size_t)(N + 1) * 4);
  int*            cursor = (int*)           alloc((size_t)N * 4);
  int*            colA   = (int*)           alloc((size_t)(E + N) * 4);
  int*            bidxA  = (int*)           alloc((size_t)(E + N) * 4);

  hipMemsetAsync(Wn, 0xFF, (size_t)N * N * 4, stream);   // -1
  hipMemsetAsync(cnt, 0, (size_t)N * 4, stream);

  int MN = N * D;

  // weight casts + LN1
  cast6_kernel<<<768, 256, 0, stream>>>(Wq, Wk, Wv, Wo, W1, W2,
                                        Wqb, Wkb, Wvb, Wob, W1b, W2b);
  ln_kernel<<<N, 256, 0, stream>>>(x, ln1g, ln1b, hbf);
  // QKV (bf16 MFMA)
  dim3 g_qkv(D / 64, N / 64, 3);
  mgemm_qkv<<<g_qkv, 256, 0, stream>>>(hbf, Wqb, Wkb, Wvb, bq, bk, bv,
                                       Qd, Kd, Vd, N, D, D);
  // edge bias + CSR (.set-winner dedupe)
  edge_bias_kernel<<<(E + 255) / 256, 256, 0, stream>>>(ea, We, be, ebuf, E);
  winner_kernel<<<(E + 255) / 256, 256, 0, stream>>>(ei, Wn, E, N);
  count_kernel<<<(E + 255) / 256, 256, 0, stream>>>(ei, Wn, cnt, E, N);
  self_count_kernel<<<(N + 255) / 256, 256, 0, stream>>>(Wn, cnt, N);
  scan_kernel<<<1, 256, 0, stream>>>(cnt, rowptr, cursor, N);
  scatter_kernel<<<(E + 255) / 256, 256, 0, stream>>>(ei, Wn, cursor, colA, bidxA, E, N);
  self_scatter_kernel<<<(N + 255) / 256, 256, 0, stream>>>(Wn, cursor, colA, bidxA, N);
  // attention -> bf16
  attn_kernel<<<(N + 3) / 4, 256, 0, stream>>>(Qd, Kd, Vd, ebuf, rowptr, colA, bidxA,
                                               attnbf, N);
  // output proj (split-K=2) + bias + residual -> x_mid
  {
    dim3 g(D / 64, N / 64, 2);
    mgemm_splitk<<<g, 256, 0, stream>>>(attnbf, Wob, P, N, D, D, D / 2);
    reduce_kernel<<<(MN / 4 + 255) / 256, 256, 0, stream>>>(P, bo, x, x_mid, MN, D, 2);
  }
  // LN2 + FFN
  ln_kernel<<<N, 256, 0, stream>>>(x_mid, ln2g, ln2b, hbf);
  dim3 g_1(4 * D / 64, N / 64, 1);
  mgemm_gelu<<<g_1, 256, 0, stream>>>(hbf, W1b, b1, tbf, N, 4 * D, D);
  // W2 (split-K=4) + bias + residual -> d_out
  {
    dim3 g(D / 64, N / 64, 4);
    mgemm_splitk<<<g, 256, 0, stream>>>(tbf, W2b, P, N, D, 4 * D, D);
    reduce_kernel<<<(MN / 4 + 255) / 256, 256, 0, stream>>>(P, b2, x_mid, (float*)d_out,
                                                            MN, D, 4);
  }
}

// Round 5
// 202.257 us; speedup vs baseline: 1.3184x; 1.1445x over previous
//
#include <hip/hip_runtime.h>
#include <math.h>

#define D 256
#define NH 8
#define HD 32
#define EDIM 64

typedef __attribute__((ext_vector_type(8))) short bfrag;   // 8 bf16 (4 VGPRs)
typedef __attribute__((ext_vector_type(4))) float ffrag;   // 4 fp32 acc

__device__ __forceinline__ unsigned short f2bf(float x) {  // RNE fp32->bf16
  unsigned int u = __float_as_uint(x);
  return (unsigned short)((u + 0x7FFFu + ((u >> 16) & 1u)) >> 16);
}

// ---------------------------------------------------------------- fused prep:
// blocks [0, CB):               weight cast fp32->bf16 (6 regions)
// blocks [CB, CB+N):            LayerNorm1 -> bf16
// blocks [CB+N, CB+N+EB):       per-source edge count (atomicAdd)
// blocks [CB+N+EB, CB+N+2*EB):  edge bias eb[e,h]
__global__ __launch_bounds__(256) void prep_kernel(
    const float* __restrict__ s0, const float* __restrict__ s1,
    const float* __restrict__ s2, const float* __restrict__ s3,
    const float* __restrict__ s4, const float* __restrict__ s5,
    unsigned short* __restrict__ d0, unsigned short* __restrict__ d1,
    unsigned short* __restrict__ d2, unsigned short* __restrict__ d3,
    unsigned short* __restrict__ d4, unsigned short* __restrict__ d5,
    const float* __restrict__ x, const float* __restrict__ g,
    const float* __restrict__ b, unsigned short* __restrict__ hbf,
    const int* __restrict__ ei, int* __restrict__ cnt,
    const float* __restrict__ ea, const float* __restrict__ We,
    const float* __restrict__ be, float* __restrict__ eb,
    int N, int E, int CB, int EB) {
  int blk = blockIdx.x;
  int tid = threadIdx.x;
  if (blk < CB) {                       // ---- weight cast
    int i = (blk * 256 + tid) * 4;
    const float* s; unsigned short* d; int off;
    if      (i < 65536)  { s = s0; d = d0; off = i; }
    else if (i < 131072) { s = s1; d = d1; off = i - 65536; }
    else if (i < 196608) { s = s2; d = d2; off = i - 131072; }
    else if (i < 262144) { s = s3; d = d3; off = i - 196608; }
    else if (i < 524288) { s = s4; d = d4; off = i - 262144; }
    else if (i < 786432) { s = s5; d = d5; off = i - 524288; }
    else return;
    float4 v = *(const float4*)(s + off);
    *(ushort4*)(d + off) = make_ushort4(f2bf(v.x), f2bf(v.y), f2bf(v.z), f2bf(v.w));
  } else if (blk < CB + N) {            // ---- LayerNorm1
    int row = blk - CB;
    float v = x[row * D + tid];
    float s = v, sq = v * v;
    #pragma unroll
    for (int m = 1; m < 64; m <<= 1) { s += __shfl_xor(s, m); sq += __shfl_xor(sq, m); }
    __shared__ float ps[4], pq[4];
    int wid = tid >> 6, lane = tid & 63;
    if (lane == 0) { ps[wid] = s; pq[wid] = sq; }
    __syncthreads();
    float ts = ps[0] + ps[1] + ps[2] + ps[3];
    float tq = pq[0] + pq[1] + pq[2] + pq[3];
    float mu  = ts * (1.f / D);
    float var = tq * (1.f / D) - mu * mu;
    float inv = 1.f / sqrtf(var + 1e-5f);
    hbf[row * D + tid] = f2bf((v - mu) * inv * g[tid] + b[tid]);
  } else if (blk < CB + N + EB) {       // ---- edge count by source
    int e = (blk - CB - N) * 256 + tid;
    if (e < E) atomicAdd(&cnt[ei[e]], 1);
  } else {                              // ---- edge bias
    int e = (blk - CB - N - EB) * 256 + tid;
    if (e >= E) return;
    const float* row = ea + (size_t)e * EDIM;
    float acc[NH];
    #pragma unroll
    for (int h = 0; h < NH; h++) acc[h] = be[h];
    #pragma unroll 4
    for (int k = 0; k < EDIM; k++) {
      float r = row[k];
      #pragma unroll
      for (int h = 0; h < NH; h++) acc[h] = fmaf(r, We[k * NH + h], acc[h]);
    }
    #pragma unroll
    for (int h = 0; h < NH; h++) eb[e * NH + h] = acc[h];
  }
}

// ---------------------------------------------------------------- exclusive scan cnt[N] -> rowptr[N+1], cursor[N]
__global__ __launch_bounds__(256) void scan_kernel(const int* __restrict__ cnt,
    int* __restrict__ rowptr, int* __restrict__ cursor, int N) {
  __shared__ int part[256];
  int tid = threadIdx.x;
  int chunk = (N + 255) / 256;
  int base = tid * chunk;
  int s = 0;
  for (int i = 0; i < chunk; i++) { int idx = base + i; if (idx < N) s += cnt[idx]; }
  part[tid] = s;
  __syncthreads();
  for (int off = 1; off < 256; off <<= 1) {
    int v = (tid >= off) ? part[tid - off] : 0;
    __syncthreads();
    part[tid] += v;
    __syncthreads();
  }
  int run = (tid == 0) ? 0 : part[tid - 1];
  for (int i = 0; i < chunk; i++) {
    int idx = base + i;
    if (idx < N) { rowptr[idx] = run; cursor[idx] = run; run += cnt[idx]; }
  }
  if (tid == 255) rowptr[N] = part[255];
}

// ---------------------------------------------------------------- scatter ALL edges into CSR (no dedupe)
__global__ void scatter_kernel(const int* __restrict__ ei, int* __restrict__ cursor,
    int* __restrict__ col, int* __restrict__ eidx, int E) {
  int e = blockIdx.x * 256 + threadIdx.x;
  if (e >= E) return;
  int s = ei[e], d = ei[E + e];
  int p = atomicAdd(&cursor[s], 1);
  col[p] = d; eidx[p] = e;
}

// ---------------------------------------------------------------- bf16 MFMA GEMM core (validated r4)
// A:[M,K] bf16 row-major, B:[K,Nn] bf16 row-major. 64x64 tile, BK=32,
// 256 threads = 4 waves. LDS pitch 80 B. Frag layouts per learn_hip m89/m91.
__device__ __forceinline__ void mg_core(const unsigned short* __restrict__ A,
    const unsigned short* __restrict__ B, int K, int Nn, int bm, int bn,
    int kb0, int kb1, unsigned short (*As)[40], unsigned short (*Bt)[40],
    ffrag acc[4]) {
  int tid = threadIdx.x;
  int wid = tid >> 6, lane = tid & 63;
  int lr = lane & 15, lk = lane >> 4;
  int ar = tid >> 2, ak = (tid & 3) * 8;
  int bnn = tid & 63, bkg = tid >> 6;
  for (int kb = kb0; kb < kb1; kb += 32) {
    uint4 av = *(const uint4*)(A + (size_t)(bm + ar) * K + kb + ak);
    *(uint4*)&As[ar][ak] = av;
    unsigned int u[4];
    #pragma unroll
    for (int jj = 0; jj < 4; jj++) {
      unsigned short lo = B[(size_t)(kb + bkg * 8 + 2 * jj)     * Nn + bn + bnn];
      unsigned short hi = B[(size_t)(kb + bkg * 8 + 2 * jj + 1) * Nn + bn + bnn];
      u[jj] = (unsigned int)lo | ((unsigned int)hi << 16);
    }
    *(uint4*)&Bt[bnn][bkg * 8] = make_uint4(u[0], u[1], u[2], u[3]);
    __syncthreads();
    bfrag af = *(const bfrag*)&As[wid * 16 + lr][lk * 8];
    #pragma unroll
    for (int nf = 0; nf < 4; nf++) {
      bfrag bf = *(const bfrag*)&Bt[nf * 16 + lr][lk * 8];
      acc[nf] = __builtin_amdgcn_mfma_f32_16x16x32_bf16(af, bf, acc[nf], 0, 0, 0);
    }
    __syncthreads();
  }
}

__global__ __launch_bounds__(256) void mgemm_qkv(const unsigned short* __restrict__ A,
    const unsigned short* __restrict__ B0, const unsigned short* __restrict__ B1,
    const unsigned short* __restrict__ B2,
    const float* __restrict__ b0, const float* __restrict__ b1, const float* __restrict__ b2,
    float* __restrict__ C0, float* __restrict__ C1, float* __restrict__ C2,
    int M, int Nn, int K) {
  __shared__ __align__(16) unsigned short As[64][40];
  __shared__ __align__(16) unsigned short Bt[64][40];
  int z = blockIdx.z;
  const unsigned short* B = (z == 0) ? B0 : (z == 1) ? B1 : B2;
  const float* bias = (z == 0) ? b0 : (z == 1) ? b1 : b2;
  float* C = (z == 0) ? C0 : (z == 1) ? C1 : C2;
  int bm = blockIdx.y * 64, bn = blockIdx.x * 64;
  ffrag acc[4] = {};
  mg_core(A, B, K, Nn, bm, bn, 0, K, As, Bt, acc);
  int lane = threadIdx.x & 63, wid = threadIdx.x >> 6;
  int lr = lane & 15, lk = lane >> 4;
  #pragma unroll
  for (int nf = 0; nf < 4; nf++) {
    int col = bn + nf * 16 + lr;
    float bv = bias[col];
    #pragma unroll
    for (int i = 0; i < 4; i++) {
      int row = bm + wid * 16 + lk * 4 + i;
      C[(size_t)row * Nn + col] = acc[nf][i] + bv;
    }
  }
}

__global__ __launch_bounds__(256) void mgemm_gelu(const unsigned short* __restrict__ A,
    const unsigned short* __restrict__ B, const float* __restrict__ bias,
    unsigned short* __restrict__ C, int M, int Nn, int K) {
  __shared__ __align__(16) unsigned short As[64][40];
  __shared__ __align__(16) unsigned short Bt[64][40];
  int bm = blockIdx.y * 64, bn = blockIdx.x * 64;
  ffrag acc[4] = {};
  mg_core(A, B, K, Nn, bm, bn, 0, K, As, Bt, acc);
  int lane = threadIdx.x & 63, wid = threadIdx.x >> 6;
  int lr = lane & 15, lk = lane >> 4;
  #pragma unroll
  for (int nf = 0; nf < 4; nf++) {
    int col = bn + nf * 16 + lr;
    float bv = bias[col];
    #pragma unroll
    for (int i = 0; i < 4; i++) {
      int row = bm + wid * 16 + lk * 4 + i;
      float v = acc[nf][i] + bv;
      v = 0.5f * v * (1.f + erff(v * 0.70710678118654752f));
      C[(size_t)row * Nn + col] = f2bf(v);
    }
  }
}

__global__ __launch_bounds__(256) void mgemm_splitk(const unsigned short* __restrict__ A,
    const unsigned short* __restrict__ B, float* __restrict__ P,
    int M, int Nn, int K, int Kslice) {
  __shared__ __align__(16) unsigned short As[64][40];
  __shared__ __align__(16) unsigned short Bt[64][40];
  int z = blockIdx.z;
  int bm = blockIdx.y * 64, bn = blockIdx.x * 64;
  ffrag acc[4] = {};
  mg_core(A, B, K, Nn, bm, bn, z * Kslice, (z + 1) * Kslice, As, Bt, acc);
  float* Pz = P + (size_t)z * M * Nn;
  int lane = threadIdx.x & 63, wid = threadIdx.x >> 6;
  int lr = lane & 15, lk = lane >> 4;
  #pragma unroll
  for (int nf = 0; nf < 4; nf++) {
    int col = bn + nf * 16 + lr;
    #pragma unroll
    for (int i = 0; i < 4; i++) {
      int row = bm + wid * 16 + lk * 4 + i;
      Pz[(size_t)row * Nn + col] = acc[nf][i];
    }
  }
}

// out = sum_s P[s] + bias + R   (final FFN reduce, S=4)
__global__ __launch_bounds__(256) void reduce_kernel(const float* __restrict__ P,
    const float* __restrict__ bias, const float* __restrict__ R,
    float* __restrict__ out, int MN, int Nn, int S) {
  int i = blockIdx.x * 256 + threadIdx.x;
  if (i * 4 >= MN) return;
  size_t b = (size_t)i * 4;
  float4 acc = *(const float4*)(P + b);
  for (int s = 1; s < S; s++) {
    float4 p = *(const float4*)(P + (size_t)s * MN + b);
    acc.x += p.x; acc.y += p.y; acc.z += p.z; acc.w += p.w;
  }
  float4 bi = *(const float4*)(bias + (b % Nn));
  float4 r  = *(const float4*)(R + b);
  acc.x += bi.x + r.x; acc.y += bi.y + r.y; acc.z += bi.z + r.z; acc.w += bi.w + r.w;
  *(float4*)(out + b) = acc;
}

// ---------------------------------------------------------------- fused Wo-reduce + residual + LayerNorm2
// x_mid = P0 + P1 + bo + x ; hbf = LN(x_mid) in bf16
__global__ __launch_bounds__(256) void ln2_fused_kernel(const float* __restrict__ P,
    const float* __restrict__ bo, const float* __restrict__ x,
    const float* __restrict__ g, const float* __restrict__ b,
    float* __restrict__ x_mid, unsigned short* __restrict__ hbf, int MN) {
  int row = blockIdx.x;
  int tid = threadIdx.x;
  size_t idx = (size_t)row * D + tid;
  float v = P[idx] + P[(size_t)MN + idx] + bo[tid] + x[idx];
  x_mid[idx] = v;
  float s = v, sq = v * v;
  #pragma unroll
  for (int m = 1; m < 64; m <<= 1) { s += __shfl_xor(s, m); sq += __shfl_xor(sq, m); }
  __shared__ float ps[4], pq[4];
  int wid = tid >> 6, lane = tid & 63;
  if (lane == 0) { ps[wid] = s; pq[wid] = sq; }
  __syncthreads();
  float ts = ps[0] + ps[1] + ps[2] + ps[3];
  float tq = pq[0] + pq[1] + pq[2] + pq[3];
  float mu  = ts * (1.f / D);
  float var = tq * (1.f / D) - mu * mu;
  float inv = 1.f / sqrtf(var + 1e-5f);
  hbf[idx] = f2bf((v - mu) * inv * g[tid] + b[tid]);
}

// ---------------------------------------------------------------- sparse attention with in-wave dedupe
// one wave per row n; lane = h*8+j owns dims [j*4, j*4+4) of head h.
// Row's CSR entries (dst, edge-id) preloaded into 4 register chunks of 64.
// Winner (.set last-wins = max edge-id) via one ballot per edge.
__global__ __launch_bounds__(256) void attn_kernel(const float* __restrict__ Q,
    const float* __restrict__ Km, const float* __restrict__ Vm,
    const float* __restrict__ eb, const int* __restrict__ rowptr,
    const int* __restrict__ col, const int* __restrict__ eidx,
    unsigned short* __restrict__ out, int N) {
  int wid = threadIdx.x >> 6, lane = threadIdx.x & 63;
  int n = blockIdx.x * 4 + wid;
  if (n >= N) return;
  int h = lane >> 3, j = lane & 7;
  int off = h * HD + j * 4;
  float4 q = *(const float4*)(Q + (size_t)n * D + off);
  int beg = rowptr[n], end = rowptr[n + 1];
  int L = end - beg;
  if (L > 256) L = 256;                    // safety cap (mean deg 32; never hit)
  int dv0 = -1, dv1 = -1, dv2 = -1, dv3 = -1;
  int ev0 = -1, ev1 = -1, ev2 = -1, ev3 = -1;
  if (lane       < L) { dv0 = col[beg + lane      ]; ev0 = eidx[beg + lane      ]; }
  if (lane +  64 < L) { dv1 = col[beg + lane +  64]; ev1 = eidx[beg + lane +  64]; }
  if (lane + 128 < L) { dv2 = col[beg + lane + 128]; ev2 = eidx[beg + lane + 128]; }
  if (lane + 192 < L) { dv3 = col[beg + lane + 192]; ev3 = eidx[beg + lane + 192]; }
  bool self_present = __any(dv0 == n) || __any(dv1 == n) ||
                      __any(dv2 == n) || __any(dv3 == n);
  float mrun = -INFINITY, srun = 0.f;
  float4 acc = make_float4(0.f, 0.f, 0.f, 0.f);

#define PROC_EDGE(m_, bias_) {                                                 \
    float4 k4 = *(const float4*)(Km + (size_t)(m_) * D + off);                 \
    float dot = q.x * k4.x + q.y * k4.y + q.z * k4.z + q.w * k4.w;             \
    dot += __shfl_xor(dot, 1); dot += __shfl_xor(dot, 2); dot += __shfl_xor(dot, 4); \
    float sc = fmaf(dot, 0.17677669529663687f, bias_);                         \
    float mnew = fmaxf(mrun, sc);                                              \
    float corr = __expf(mrun - mnew);                                          \
    float pp = __expf(sc - mnew);                                              \
    float4 v4 = *(const float4*)(Vm + (size_t)(m_) * D + off);                 \
    srun = srun * corr + pp;                                                   \
    acc.x = fmaf(acc.x, corr, pp * v4.x);                                      \
    acc.y = fmaf(acc.y, corr, pp * v4.y);                                      \
    acc.z = fmaf(acc.z, corr, pp * v4.z);                                      \
    acc.w = fmaf(acc.w, corr, pp * v4.w);                                      \
    mrun = mnew; }

#define PROC_CHUNK(dvC, evC, base_) {                                          \
    int cl = L - (base_); if (cl > 64) cl = 64;                                \
    for (int ii = 0; ii < cl; ii++) {                                          \
      int d_i = __shfl(dvC, ii);                                               \
      int e_i = __shfl(evC, ii);                                               \
      bool dom = (dv0 == d_i && ev0 > e_i) || (dv1 == d_i && ev1 > e_i) ||     \
                 (dv2 == d_i && ev2 > e_i) || (dv3 == d_i && ev3 > e_i);       \
      if (__any(dom)) continue;                                                \
      float bias_ = eb[(size_t)e_i * NH + h];                                  \
      PROC_EDGE(d_i, bias_);                                                   \
    } }

  PROC_CHUNK(dv0, ev0, 0)
  if (L > 64)  PROC_CHUNK(dv1, ev1, 64)
  if (L > 128) PROC_CHUNK(dv2, ev2, 128)
  if (L > 192) PROC_CHUNK(dv3, ev3, 192)
  if (!self_present) PROC_EDGE(n, 0.f)
#undef PROC_CHUNK
#undef PROC_EDGE

  float inv = 1.f / srun;
  ushort4 o = make_ushort4(f2bf(acc.x * inv), f2bf(acc.y * inv),
                           f2bf(acc.z * inv), f2bf(acc.w * inv));
  *(ushort4*)(out + (size_t)n * D + off) = o;
}

// ----------------------------------------------------------------
extern "C" void kernel_launch(void* const* d_in, const int* in_sizes, int n_in,
                              void* d_out, int out_size, void* d_ws, size_t ws_size,
                              hipStream_t stream) {
  const float* x    = (const float*)d_in[0];
  const int*   ei   = (const int*)d_in[1];
  const float* ea   = (const float*)d_in[2];
  const float* Wq   = (const float*)d_in[3];  const float* bq = (const float*)d_in[4];
  const float* Wk   = (const float*)d_in[5];  const float* bk = (const float*)d_in[6];
  const float* Wv   = (const float*)d_in[7];  const float* bv = (const float*)d_in[8];
  const float* Wo   = (const float*)d_in[9];  const float* bo = (const float*)d_in[10];
  const float* We   = (const float*)d_in[11]; const float* be = (const float*)d_in[12];
  const float* W1   = (const float*)d_in[13]; const float* b1 = (const float*)d_in[14];
  const float* W2   = (const float*)d_in[15]; const float* b2 = (const float*)d_in[16];
  const float* ln1g = (const float*)d_in[17]; const float* ln1b = (const float*)d_in[18];
  const float* ln2g = (const float*)d_in[19]; const float* ln2b = (const float*)d_in[20];

  int N = in_sizes[0] / D;
  int E = in_sizes[1] / 2;

  char* p = (char*)d_ws;
  auto alloc = [&](size_t bytes) -> char* {
    char* r = p; p += (bytes + 255) & ~(size_t)255; return r;
  };
  unsigned short* hbf    = (unsigned short*)alloc((size_t)N * D * 2);
  float*          Qd     = (float*)         alloc((size_t)N * D * 4);
  float*          Kd     = (float*)         alloc((size_t)N * D * 4);
  float*          Vd     = (float*)         alloc((size_t)N * D * 4);
  unsigned short* attnbf = (unsigned short*)alloc((size_t)N * D * 2);
  float*          x_mid  = (float*)         alloc((size_t)N * D * 4);
  float*          ebuf   = (float*)         alloc((size_t)E * NH * 4);
  unsigned short* tbf    = (unsigned short*)alloc((size_t)N * 4 * D * 2);
  float*          P      = (float*)         alloc((size_t)4 * N * D * 4);
  unsigned short* Wqb    = (unsigned short*)alloc((size_t)D * D * 2);
  unsigned short* Wkb    = (unsigned short*)alloc((size_t)D * D * 2);
  unsigned short* Wvb    = (unsigned short*)alloc((size_t)D * D * 2);
  unsigned short* Wob    = (unsigned short*)alloc((size_t)D * D * 2);
  unsigned short* W1b    = (unsigned short*)alloc((size_t)D * 4 * D * 2);
  unsigned short* W2b    = (unsigned short*)alloc((size_t)4 * D * D * 2);
  int*            cnt    = (int*)           alloc((size_t)N * 4);
  int*            rowptr = (int*)           alloc((size_t)(N + 1) * 4);
  int*            cursor = (int*)           alloc((size_t)N * 4);
  int*            colA   = (int*)           alloc((size_t)E * 4);
  int*            eidxA  = (int*)           alloc((size_t)E * 4);

  hipMemsetAsync(cnt, 0, (size_t)N * 4, stream);

  int MN = N * D;
  int CB = 768;                     // cast blocks (786432/4/256)
  int EB = (E + 255) / 256;

  // prep: cast + LN1 + count + edge-bias (one dispatch)
  prep_kernel<<<CB + N + 2 * EB, 256, 0, stream>>>(
      Wq, Wk, Wv, Wo, W1, W2, Wqb, Wkb, Wvb, Wob, W1b, W2b,
      x, ln1g, ln1b, hbf, ei, cnt, ea, We, be, ebuf, N, E, CB, EB);
  // CSR build
  scan_kernel<<<1, 256, 0, stream>>>(cnt, rowptr, cursor, N);
  scatter_kernel<<<EB, 256, 0, stream>>>(ei, cursor, colA, eidxA, E);
  // QKV (bf16 MFMA)
  dim3 g_qkv(D / 64, N / 64, 3);
  mgemm_qkv<<<g_qkv, 256, 0, stream>>>(hbf, Wqb, Wkb, Wvb, bq, bk, bv,
                                       Qd, Kd, Vd, N, D, D);
  // attention (in-wave dedupe + self-loop) -> bf16
  attn_kernel<<<(N + 3) / 4, 256, 0, stream>>>(Qd, Kd, Vd, ebuf, rowptr, colA, eidxA,
                                               attnbf, N);
  // output proj (split-K=2); reduce fused into LN2
  {
    dim3 g(D / 64, N / 64, 2);
    mgemm_splitk<<<g, 256, 0, stream>>>(attnbf, Wob, P, N, D, D, D / 2);
    ln2_fused_kernel<<<N, 256, 0, stream>>>(P, bo, x, ln2g, ln2b, x_mid, hbf, MN);
  }
  // FFN
  dim3 g_1(4 * D / 64, N / 64, 1);
  mgemm_gelu<<<g_1, 256, 0, stream>>>(hbf, W1b, b1, tbf, N, 4 * D, D);
  {
    dim3 g(D / 64, N / 64, 4);
    mgemm_splitk<<<g, 256, 0, stream>>>(tbf, W2b, P, N, D, 4 * D, D);
    reduce_kernel<<<(MN / 4 + 255) / 256, 256, 0, stream>>>(P, b2, x_mid, (float*)d_out,
                                                            MN, D, 4);
  }
}

// Round 6
// 197.619 us; speedup vs baseline: 1.3493x; 1.0235x over previous
//
#include <hip/hip_runtime.h>
#include <math.h>

#define D 256
#define NH 8
#define HD 32
#define EDIM 64
#define MAXDEG 192

typedef __attribute__((ext_vector_type(8))) short bfrag;   // 8 bf16 (4 VGPRs)
typedef __attribute__((ext_vector_type(4))) float ffrag;   // 4 fp32 acc

__device__ __forceinline__ unsigned short f2bf(float x) {  // RNE fp32->bf16
  unsigned int u = __float_as_uint(x);
  return (unsigned short)((u + 0x7FFFu + ((u >> 16) & 1u)) >> 16);
}

// ---------------------------------------------------------------- fused prep:
// blocks [0, CB):               weight cast fp32->bf16 (6 regions)
// blocks [CB, CB+N):            LayerNorm1 -> bf16
// blocks [CB+N, CB+N+EB):       edge bias eb[e,h]
// blocks [CB+N+EB, CB+N+2*EB):  scatter edges into padded adjacency
__global__ __launch_bounds__(256) void prep_kernel(
    const float* __restrict__ s0, const float* __restrict__ s1,
    const float* __restrict__ s2, const float* __restrict__ s3,
    const float* __restrict__ s4, const float* __restrict__ s5,
    unsigned short* __restrict__ d0, unsigned short* __restrict__ d1,
    unsigned short* __restrict__ d2, unsigned short* __restrict__ d3,
    unsigned short* __restrict__ d4, unsigned short* __restrict__ d5,
    const float* __restrict__ x, const float* __restrict__ g,
    const float* __restrict__ b, unsigned short* __restrict__ hbf,
    const int* __restrict__ ei, int* __restrict__ cnt,
    int* __restrict__ colp, int* __restrict__ eidxp,
    const float* __restrict__ ea, const float* __restrict__ We,
    const float* __restrict__ be, float* __restrict__ eb,
    int N, int E, int CB, int EB) {
  int blk = blockIdx.x;
  int tid = threadIdx.x;
  if (blk < CB) {                       // ---- weight cast
    int i = (blk * 256 + tid) * 4;
    const float* s; unsigned short* d; int off;
    if      (i < 65536)  { s = s0; d = d0; off = i; }
    else if (i < 131072) { s = s1; d = d1; off = i - 65536; }
    else if (i < 196608) { s = s2; d = d2; off = i - 131072; }
    else if (i < 262144) { s = s3; d = d3; off = i - 196608; }
    else if (i < 524288) { s = s4; d = d4; off = i - 262144; }
    else if (i < 786432) { s = s5; d = d5; off = i - 524288; }
    else return;
    float4 v = *(const float4*)(s + off);
    *(ushort4*)(d + off) = make_ushort4(f2bf(v.x), f2bf(v.y), f2bf(v.z), f2bf(v.w));
  } else if (blk < CB + N) {            // ---- LayerNorm1
    int row = blk - CB;
    float v = x[row * D + tid];
    float s = v, sq = v * v;
    #pragma unroll
    for (int m = 1; m < 64; m <<= 1) { s += __shfl_xor(s, m); sq += __shfl_xor(sq, m); }
    __shared__ float ps[4], pq[4];
    int wid = tid >> 6, lane = tid & 63;
    if (lane == 0) { ps[wid] = s; pq[wid] = sq; }
    __syncthreads();
    float ts = ps[0] + ps[1] + ps[2] + ps[3];
    float tq = pq[0] + pq[1] + pq[2] + pq[3];
    float mu  = ts * (1.f / D);
    float var = tq * (1.f / D) - mu * mu;
    float inv = 1.f / sqrtf(var + 1e-5f);
    hbf[row * D + tid] = f2bf((v - mu) * inv * g[tid] + b[tid]);
  } else if (blk < CB + N + EB) {       // ---- edge bias
    int e = (blk - CB - N) * 256 + tid;
    if (e >= E) return;
    const float* row = ea + (size_t)e * EDIM;
    float acc[NH];
    #pragma unroll
    for (int h = 0; h < NH; h++) acc[h] = be[h];
    #pragma unroll 4
    for (int k = 0; k < EDIM; k++) {
      float r = row[k];
      #pragma unroll
      for (int h = 0; h < NH; h++) acc[h] = fmaf(r, We[k * NH + h], acc[h]);
    }
    #pragma unroll
    for (int h = 0; h < NH; h++) eb[e * NH + h] = acc[h];
  } else {                              // ---- scatter into padded adjacency
    int e = (blk - CB - N - EB) * 256 + tid;
    if (e >= E) return;
    int s = ei[e], d = ei[E + e];
    int pos = atomicAdd(&cnt[s], 1);
    if (pos < MAXDEG) {
      colp [(size_t)s * MAXDEG + pos] = d;
      eidxp[(size_t)s * MAXDEG + pos] = e;
    }
  }
}

// ---------------------------------------------------------------- bf16 MFMA GEMM core (validated r4/r5)
// A:[M,K] bf16 row-major, B:[K,Nn] bf16 row-major. 64x64 tile, BK=32,
// 256 threads = 4 waves. LDS pitch 80 B. Frag layouts per learn_hip m89/m91.
__device__ __forceinline__ void mg_core(const unsigned short* __restrict__ A,
    const unsigned short* __restrict__ B, int K, int Nn, int bm, int bn,
    int kb0, int kb1, unsigned short (*As)[40], unsigned short (*Bt)[40],
    ffrag acc[4]) {
  int tid = threadIdx.x;
  int wid = tid >> 6, lane = tid & 63;
  int lr = lane & 15, lk = lane >> 4;
  int ar = tid >> 2, ak = (tid & 3) * 8;
  int bnn = tid & 63, bkg = tid >> 6;
  for (int kb = kb0; kb < kb1; kb += 32) {
    uint4 av = *(const uint4*)(A + (size_t)(bm + ar) * K + kb + ak);
    *(uint4*)&As[ar][ak] = av;
    unsigned int u[4];
    #pragma unroll
    for (int jj = 0; jj < 4; jj++) {
      unsigned short lo = B[(size_t)(kb + bkg * 8 + 2 * jj)     * Nn + bn + bnn];
      unsigned short hi = B[(size_t)(kb + bkg * 8 + 2 * jj + 1) * Nn + bn + bnn];
      u[jj] = (unsigned int)lo | ((unsigned int)hi << 16);
    }
    *(uint4*)&Bt[bnn][bkg * 8] = make_uint4(u[0], u[1], u[2], u[3]);
    __syncthreads();
    bfrag af = *(const bfrag*)&As[wid * 16 + lr][lk * 8];
    #pragma unroll
    for (int nf = 0; nf < 4; nf++) {
      bfrag bf = *(const bfrag*)&Bt[nf * 16 + lr][lk * 8];
      acc[nf] = __builtin_amdgcn_mfma_f32_16x16x32_bf16(af, bf, acc[nf], 0, 0, 0);
    }
    __syncthreads();
  }
}

// QKV: z selects weight/bias/output. fp32 out = acc + bias.
__global__ __launch_bounds__(256) void mgemm_qkv(const unsigned short* __restrict__ A,
    const unsigned short* __restrict__ B0, const unsigned short* __restrict__ B1,
    const unsigned short* __restrict__ B2,
    const float* __restrict__ b0, const float* __restrict__ b1, const float* __restrict__ b2,
    float* __restrict__ C0, float* __restrict__ C1, float* __restrict__ C2,
    int M, int Nn, int K) {
  __shared__ __align__(16) unsigned short As[64][40];
  __shared__ __align__(16) unsigned short Bt[64][40];
  int z = blockIdx.z;
  const unsigned short* B = (z == 0) ? B0 : (z == 1) ? B1 : B2;
  const float* bias = (z == 0) ? b0 : (z == 1) ? b1 : b2;
  float* C = (z == 0) ? C0 : (z == 1) ? C1 : C2;
  int bm = blockIdx.y * 64, bn = blockIdx.x * 64;
  ffrag acc[4] = {};
  mg_core(A, B, K, Nn, bm, bn, 0, K, As, Bt, acc);
  int lane = threadIdx.x & 63, wid = threadIdx.x >> 6;
  int lr = lane & 15, lk = lane >> 4;
  #pragma unroll
  for (int nf = 0; nf < 4; nf++) {
    int col = bn + nf * 16 + lr;
    float bv = bias[col];
    #pragma unroll
    for (int i = 0; i < 4; i++) {
      int row = bm + wid * 16 + lk * 4 + i;
      C[(size_t)row * Nn + col] = acc[nf][i] + bv;
    }
  }
}

// fp32 out = acc + bias + R  (Wo and W2 paths; no split-K)
__global__ __launch_bounds__(256) void mgemm_res(const unsigned short* __restrict__ A,
    const unsigned short* __restrict__ B, const float* __restrict__ bias,
    const float* __restrict__ R, float* __restrict__ C, int M, int Nn, int K) {
  __shared__ __align__(16) unsigned short As[64][40];
  __shared__ __align__(16) unsigned short Bt[64][40];
  int bm = blockIdx.y * 64, bn = blockIdx.x * 64;
  ffrag acc[4] = {};
  mg_core(A, B, K, Nn, bm, bn, 0, K, As, Bt, acc);
  int lane = threadIdx.x & 63, wid = threadIdx.x >> 6;
  int lr = lane & 15, lk = lane >> 4;
  #pragma unroll
  for (int nf = 0; nf < 4; nf++) {
    int col = bn + nf * 16 + lr;
    float bv = bias[col];
    #pragma unroll
    for (int i = 0; i < 4; i++) {
      int row = bm + wid * 16 + lk * 4 + i;
      C[(size_t)row * Nn + col] = acc[nf][i] + bv + R[(size_t)row * Nn + col];
    }
  }
}

// bf16 out = gelu(acc + bias)  (W1)
__global__ __launch_bounds__(256) void mgemm_gelu(const unsigned short* __restrict__ A,
    const unsigned short* __restrict__ B, const float* __restrict__ bias,
    unsigned short* __restrict__ C, int M, int Nn, int K) {
  __shared__ __align__(16) unsigned short As[64][40];
  __shared__ __align__(16) unsigned short Bt[64][40];
  int bm = blockIdx.y * 64, bn = blockIdx.x * 64;
  ffrag acc[4] = {};
  mg_core(A, B, K, Nn, bm, bn, 0, K, As, Bt, acc);
  int lane = threadIdx.x & 63, wid = threadIdx.x >> 6;
  int lr = lane & 15, lk = lane >> 4;
  #pragma unroll
  for (int nf = 0; nf < 4; nf++) {
    int col = bn + nf * 16 + lr;
    float bv = bias[col];
    #pragma unroll
    for (int i = 0; i < 4; i++) {
      int row = bm + wid * 16 + lk * 4 + i;
      float v = acc[nf][i] + bv;
      v = 0.5f * v * (1.f + erff(v * 0.70710678118654752f));
      C[(size_t)row * Nn + col] = f2bf(v);
    }
  }
}

// ---------------------------------------------------------------- LayerNorm2 (x_mid -> hbf bf16)
__global__ __launch_bounds__(256) void ln2_kernel(const float* __restrict__ x,
    const float* __restrict__ g, const float* __restrict__ b,
    unsigned short* __restrict__ out) {
  int row = blockIdx.x;
  int tid = threadIdx.x;
  float v = x[row * D + tid];
  float s = v, sq = v * v;
  #pragma unroll
  for (int m = 1; m < 64; m <<= 1) { s += __shfl_xor(s, m); sq += __shfl_xor(sq, m); }
  __shared__ float ps[4], pq[4];
  int wid = tid >> 6, lane = tid & 63;
  if (lane == 0) { ps[wid] = s; pq[wid] = sq; }
  __syncthreads();
  float ts = ps[0] + ps[1] + ps[2] + ps[3];
  float tq = pq[0] + pq[1] + pq[2] + pq[3];
  float mu  = ts * (1.f / D);
  float var = tq * (1.f / D) - mu * mu;
  float inv = 1.f / sqrtf(var + 1e-5f);
  out[row * D + tid] = f2bf((v - mu) * inv * g[tid] + b[tid]);
}

// ---------------------------------------------------------------- sparse attention with in-wave dedupe
// one wave per row n; lane = h*8+j owns dims [j*4, j*4+4) of head h.
// Row's padded-adjacency entries (dst, edge-id) preloaded into 3 register
// chunks of 64. Winner (.set last-wins = max edge-id) via one ballot per edge.
__global__ __launch_bounds__(256) void attn_kernel(const float* __restrict__ Q,
    const float* __restrict__ Km, const float* __restrict__ Vm,
    const float* __restrict__ eb, const int* __restrict__ cnt,
    const int* __restrict__ colp, const int* __restrict__ eidxp,
    unsigned short* __restrict__ out, int N) {
  int wid = threadIdx.x >> 6, lane = threadIdx.x & 63;
  int n = blockIdx.x * 4 + wid;
  if (n >= N) return;
  int h = lane >> 3, j = lane & 7;
  int off = h * HD + j * 4;
  float4 q = *(const float4*)(Q + (size_t)n * D + off);
  int L = cnt[n];
  if (L > MAXDEG) L = MAXDEG;
  size_t base = (size_t)n * MAXDEG;
  int dv0 = -1, dv1 = -1, dv2 = -1;
  int ev0 = -1, ev1 = -1, ev2 = -1;
  if (lane       < L) { dv0 = colp[base + lane      ]; ev0 = eidxp[base + lane      ]; }
  if (lane +  64 < L) { dv1 = colp[base + lane +  64]; ev1 = eidxp[base + lane +  64]; }
  if (lane + 128 < L) { dv2 = colp[base + lane + 128]; ev2 = eidxp[base + lane + 128]; }
  bool self_present = __any(dv0 == n) || __any(dv1 == n) || __any(dv2 == n);
  float mrun = -INFINITY, srun = 0.f;
  float4 acc = make_float4(0.f, 0.f, 0.f, 0.f);

#define PROC_EDGE(m_, bias_) {                                                 \
    float4 k4 = *(const float4*)(Km + (size_t)(m_) * D + off);                 \
    float dot = q.x * k4.x + q.y * k4.y + q.z * k4.z + q.w * k4.w;             \
    dot += __shfl_xor(dot, 1); dot += __shfl_xor(dot, 2); dot += __shfl_xor(dot, 4); \
    float sc = fmaf(dot, 0.17677669529663687f, bias_);                         \
    float mnew = fmaxf(mrun, sc);                                              \
    float corr = __expf(mrun - mnew);                                          \
    float pp = __expf(sc - mnew);                                              \
    float4 v4 = *(const float4*)(Vm + (size_t)(m_) * D + off);                 \
    srun = srun * corr + pp;                                                   \
    acc.x = fmaf(acc.x, corr, pp * v4.x);                                      \
    acc.y = fmaf(acc.y, corr, pp * v4.y);                                      \
    acc.z = fmaf(acc.z, corr, pp * v4.z);                                      \
    acc.w = fmaf(acc.w, corr, pp * v4.w);                                      \
    mrun = mnew; }

#define PROC_CHUNK(dvC, evC, base_) {                                          \
    int cl = L - (base_); if (cl > 64) cl = 64;                                \
    for (int ii = 0; ii < cl; ii++) {                                          \
      int d_i = __shfl(dvC, ii);                                               \
      int e_i = __shfl(evC, ii);                                               \
      bool dom = (dv0 == d_i && ev0 > e_i) || (dv1 == d_i && ev1 > e_i) ||     \
                 (dv2 == d_i && ev2 > e_i);                                    \
      if (__any(dom)) continue;                                                \
      float bias_ = eb[(size_t)e_i * NH + h];                                  \
      PROC_EDGE(d_i, bias_);                                                   \
    } }

  PROC_CHUNK(dv0, ev0, 0)
  if (L > 64)  PROC_CHUNK(dv1, ev1, 64)
  if (L > 128) PROC_CHUNK(dv2, ev2, 128)
  if (!self_present) PROC_EDGE(n, 0.f)
#undef PROC_CHUNK
#undef PROC_EDGE

  float inv = 1.f / srun;
  ushort4 o = make_ushort4(f2bf(acc.x * inv), f2bf(acc.y * inv),
                           f2bf(acc.z * inv), f2bf(acc.w * inv));
  *(ushort4*)(out + (size_t)n * D + off) = o;
}

// ----------------------------------------------------------------
extern "C" void kernel_launch(void* const* d_in, const int* in_sizes, int n_in,
                              void* d_out, int out_size, void* d_ws, size_t ws_size,
                              hipStream_t stream) {
  const float* x    = (const float*)d_in[0];
  const int*   ei   = (const int*)d_in[1];
  const float* ea   = (const float*)d_in[2];
  const float* Wq   = (const float*)d_in[3];  const float* bq = (const float*)d_in[4];
  const float* Wk   = (const float*)d_in[5];  const float* bk = (const float*)d_in[6];
  const float* Wv   = (const float*)d_in[7];  const float* bv = (const float*)d_in[8];
  const float* Wo   = (const float*)d_in[9];  const float* bo = (const float*)d_in[10];
  const float* We   = (const float*)d_in[11]; const float* be = (const float*)d_in[12];
  const float* W1   = (const float*)d_in[13]; const float* b1 = (const float*)d_in[14];
  const float* W2   = (const float*)d_in[15]; const float* b2 = (const float*)d_in[16];
  const float* ln1g = (const float*)d_in[17]; const float* ln1b = (const float*)d_in[18];
  const float* ln2g = (const float*)d_in[19]; const float* ln2b = (const float*)d_in[20];

  int N = in_sizes[0] / D;
  int E = in_sizes[1] / 2;

  char* p = (char*)d_ws;
  auto alloc = [&](size_t bytes) -> char* {
    char* r = p; p += (bytes + 255) & ~(size_t)255; return r;
  };
  unsigned short* hbf    = (unsigned short*)alloc((size_t)N * D * 2);
  float*          Qd     = (float*)         alloc((size_t)N * D * 4);
  float*          Kd     = (float*)         alloc((size_t)N * D * 4);
  float*          Vd     = (float*)         alloc((size_t)N * D * 4);
  unsigned short* attnbf = (unsigned short*)alloc((size_t)N * D * 2);
  float*          x_mid  = (float*)         alloc((size_t)N * D * 4);
  float*          ebuf   = (float*)         alloc((size_t)E * NH * 4);
  unsigned short* tbf    = (unsigned short*)alloc((size_t)N * 4 * D * 2);
  unsigned short* Wqb    = (unsigned short*)alloc((size_t)D * D * 2);
  unsigned short* Wkb    = (unsigned short*)alloc((size_t)D * D * 2);
  unsigned short* Wvb    = (unsigned short*)alloc((size_t)D * D * 2);
  unsigned short* Wob    = (unsigned short*)alloc((size_t)D * D * 2);
  unsigned short* W1b    = (unsigned short*)alloc((size_t)D * 4 * D * 2);
  unsigned short* W2b    = (unsigned short*)alloc((size_t)4 * D * D * 2);
  int*            cnt    = (int*)           alloc((size_t)N * 4);
  int*            colp   = (int*)           alloc((size_t)N * MAXDEG * 4);
  int*            eidxp  = (int*)           alloc((size_t)N * MAXDEG * 4);

  hipMemsetAsync(cnt, 0, (size_t)N * 4, stream);

  int CB = 768;                     // cast blocks (786432/4/256)
  int EB = (E + 255) / 256;

  // prep: cast + LN1 + edge-bias + scatter (one node)
  prep_kernel<<<CB + N + 2 * EB, 256, 0, stream>>>(
      Wq, Wk, Wv, Wo, W1, W2, Wqb, Wkb, Wvb, Wob, W1b, W2b,
      x, ln1g, ln1b, hbf, ei, cnt, colp, eidxp, ea, We, be, ebuf, N, E, CB, EB);
  // QKV (bf16 MFMA)
  dim3 g_qkv(D / 64, N / 64, 3);
  mgemm_qkv<<<g_qkv, 256, 0, stream>>>(hbf, Wqb, Wkb, Wvb, bq, bk, bv,
                                       Qd, Kd, Vd, N, D, D);
  // attention (in-wave dedupe + self-loop) -> bf16
  attn_kernel<<<(N + 3) / 4, 256, 0, stream>>>(Qd, Kd, Vd, ebuf, cnt, colp, eidxp,
                                               attnbf, N);
  // output proj + bias + residual -> x_mid
  dim3 g_o(D / 64, N / 64);
  mgemm_res<<<g_o, 256, 0, stream>>>(attnbf, Wob, bo, x, x_mid, N, D, D);
  // LN2
  ln2_kernel<<<N, 256, 0, stream>>>(x_mid, ln2g, ln2b, hbf);
  // FFN
  dim3 g_1(4 * D / 64, N / 64);
  mgemm_gelu<<<g_1, 256, 0, stream>>>(hbf, W1b, b1, tbf, N, 4 * D, D);
  mgemm_res<<<g_o, 256, 0, stream>>>(tbf, W2b, b2, x_mid, (float*)d_out, N, D, 4 * D);
}

// Round 8
// 187.291 us; speedup vs baseline: 1.4237x; 1.0551x over previous
//
#include <hip/hip_runtime.h>
#include <math.h>

#define D 256
#define NH 8
#define HD 32
#define EDIM 64
#define MAXDEG 192

typedef __attribute__((ext_vector_type(8))) short bfrag;   // 8 bf16 (4 VGPRs)
typedef __attribute__((ext_vector_type(4))) float ffrag;   // 4 fp32 acc

__device__ __forceinline__ unsigned short f2bf(float x) {  // RNE fp32->bf16
  unsigned int u = __float_as_uint(x);
  return (unsigned short)((u + 0x7FFFu + ((u >> 16) & 1u)) >> 16);
}

// ---------------------------------------------------------------- fused prep:
// blocks [0, CB):               weight cast fp32->bf16 (6 regions)
// blocks [CB, CB+N):            LayerNorm1 -> bf16
// blocks [CB+N, CB+N+EB):       edge bias eb[e,h]
// blocks [CB+N+EB, CB+N+2*EB):  scatter edges into padded adjacency
__global__ __launch_bounds__(256) void prep_kernel(
    const float* __restrict__ s0, const float* __restrict__ s1,
    const float* __restrict__ s2, const float* __restrict__ s3,
    const float* __restrict__ s4, const float* __restrict__ s5,
    unsigned short* __restrict__ d0, unsigned short* __restrict__ d1,
    unsigned short* __restrict__ d2, unsigned short* __restrict__ d3,
    unsigned short* __restrict__ d4, unsigned short* __restrict__ d5,
    const float* __restrict__ x, const float* __restrict__ g,
    const float* __restrict__ b, unsigned short* __restrict__ hbf,
    const int* __restrict__ ei, int* __restrict__ cnt,
    int* __restrict__ colp, int* __restrict__ eidxp,
    const float* __restrict__ ea, const float* __restrict__ We,
    const float* __restrict__ be, float* __restrict__ eb,
    int N, int E, int CB, int EB) {
  int blk = blockIdx.x;
  int tid = threadIdx.x;
  if (blk < CB) {                       // ---- weight cast
    int i = (blk * 256 + tid) * 4;
    const float* s; unsigned short* d; int off;
    if      (i < 65536)  { s = s0; d = d0; off = i; }
    else if (i < 131072) { s = s1; d = d1; off = i - 65536; }
    else if (i < 196608) { s = s2; d = d2; off = i - 131072; }
    else if (i < 262144) { s = s3; d = d3; off = i - 196608; }
    else if (i < 524288) { s = s4; d = d4; off = i - 262144; }
    else if (i < 786432) { s = s5; d = d5; off = i - 524288; }
    else return;
    float4 v = *(const float4*)(s + off);
    *(ushort4*)(d + off) = make_ushort4(f2bf(v.x), f2bf(v.y), f2bf(v.z), f2bf(v.w));
  } else if (blk < CB + N) {            // ---- LayerNorm1
    int row = blk - CB;
    float v = x[row * D + tid];
    float s = v, sq = v * v;
    #pragma unroll
    for (int m = 1; m < 64; m <<= 1) { s += __shfl_xor(s, m); sq += __shfl_xor(sq, m); }
    __shared__ float ps[4], pq[4];
    int wid = tid >> 6, lane = tid & 63;
    if (lane == 0) { ps[wid] = s; pq[wid] = sq; }
    __syncthreads();
    float ts = ps[0] + ps[1] + ps[2] + ps[3];
    float tq = pq[0] + pq[1] + pq[2] + pq[3];
    float mu  = ts * (1.f / D);
    float var = tq * (1.f / D) - mu * mu;
    float inv = 1.f / sqrtf(var + 1e-5f);
    hbf[row * D + tid] = f2bf((v - mu) * inv * g[tid] + b[tid]);
  } else if (blk < CB + N + EB) {       // ---- edge bias
    int e = (blk - CB - N) * 256 + tid;
    if (e >= E) return;
    const float* row = ea + (size_t)e * EDIM;
    float acc[NH];
    #pragma unroll
    for (int h = 0; h < NH; h++) acc[h] = be[h];
    #pragma unroll 4
    for (int k = 0; k < EDIM; k++) {
      float r = row[k];
      #pragma unroll
      for (int h = 0; h < NH; h++) acc[h] = fmaf(r, We[k * NH + h], acc[h]);
    }
    #pragma unroll
    for (int h = 0; h < NH; h++) eb[e * NH + h] = acc[h];
  } else {                              // ---- scatter into padded adjacency
    int e = (blk - CB - N - EB) * 256 + tid;
    if (e >= E) return;
    int s = ei[e], d = ei[E + e];
    int pos = atomicAdd(&cnt[s], 1);
    if (pos < MAXDEG) {
      colp [(size_t)s * MAXDEG + pos] = d;
      eidxp[(size_t)s * MAXDEG + pos] = e;
    }
  }
}

// ---------------------------------------------------------------- bf16 MFMA GEMM core (validated r4/r5/r6)
// A:[M,K] bf16 row-major, B:[K,Nn] bf16 row-major. 64x64 tile, BK=32,
// 256 threads = 4 waves. LDS pitch 80 B. Frag layouts per learn_hip m89/m91.
__device__ __forceinline__ void mg_core(const unsigned short* __restrict__ A,
    const unsigned short* __restrict__ B, int K, int Nn, int bm, int bn,
    int kb0, int kb1, unsigned short (*As)[40], unsigned short (*Bt)[40],
    ffrag acc[4]) {
  int tid = threadIdx.x;
  int wid = tid >> 6, lane = tid & 63;
  int lr = lane & 15, lk = lane >> 4;
  int ar = tid >> 2, ak = (tid & 3) * 8;
  int bnn = tid & 63, bkg = tid >> 6;
  for (int kb = kb0; kb < kb1; kb += 32) {
    uint4 av = *(const uint4*)(A + (size_t)(bm + ar) * K + kb + ak);
    *(uint4*)&As[ar][ak] = av;
    unsigned int u[4];
    #pragma unroll
    for (int jj = 0; jj < 4; jj++) {
      unsigned short lo = B[(size_t)(kb + bkg * 8 + 2 * jj)     * Nn + bn + bnn];
      unsigned short hi = B[(size_t)(kb + bkg * 8 + 2 * jj + 1) * Nn + bn + bnn];
      u[jj] = (unsigned int)lo | ((unsigned int)hi << 16);
    }
    *(uint4*)&Bt[bnn][bkg * 8] = make_uint4(u[0], u[1], u[2], u[3]);
    __syncthreads();
    bfrag af = *(const bfrag*)&As[wid * 16 + lr][lk * 8];
    #pragma unroll
    for (int nf = 0; nf < 4; nf++) {
      bfrag bf = *(const bfrag*)&Bt[nf * 16 + lr][lk * 8];
      acc[nf] = __builtin_amdgcn_mfma_f32_16x16x32_bf16(af, bf, acc[nf], 0, 0, 0);
    }
    __syncthreads();
  }
}

// QKV: z selects weight/bias/output. fp32 out = acc + bias.
__global__ __launch_bounds__(256) void mgemm_qkv(const unsigned short* __restrict__ A,
    const unsigned short* __restrict__ B0, const unsigned short* __restrict__ B1,
    const unsigned short* __restrict__ B2,
    const float* __restrict__ b0, const float* __restrict__ b1, const float* __restrict__ b2,
    float* __restrict__ C0, float* __restrict__ C1, float* __restrict__ C2,
    int M, int Nn, int K) {
  __shared__ __align__(16) unsigned short As[64][40];
  __shared__ __align__(16) unsigned short Bt[64][40];
  int z = blockIdx.z;
  const unsigned short* B = (z == 0) ? B0 : (z == 1) ? B1 : B2;
  const float* bias = (z == 0) ? b0 : (z == 1) ? b1 : b2;
  float* C = (z == 0) ? C0 : (z == 1) ? C1 : C2;
  int bm = blockIdx.y * 64, bn = blockIdx.x * 64;
  ffrag acc[4] = {};
  mg_core(A, B, K, Nn, bm, bn, 0, K, As, Bt, acc);
  int lane = threadIdx.x & 63, wid = threadIdx.x >> 6;
  int lr = lane & 15, lk = lane >> 4;
  #pragma unroll
  for (int nf = 0; nf < 4; nf++) {
    int col = bn + nf * 16 + lr;
    float bv = bias[col];
    #pragma unroll
    for (int i = 0; i < 4; i++) {
      int row = bm + wid * 16 + lk * 4 + i;
      C[(size_t)row * Nn + col] = acc[nf][i] + bv;
    }
  }
}

// split-K partial: P[z] = A @ B over K-slice z (no bias)  [validated r5]
__global__ __launch_bounds__(256) void mgemm_splitk(const unsigned short* __restrict__ A,
    const unsigned short* __restrict__ B, float* __restrict__ P,
    int M, int Nn, int K, int Kslice) {
  __shared__ __align__(16) unsigned short As[64][40];
  __shared__ __align__(16) unsigned short Bt[64][40];
  int z = blockIdx.z;
  int bm = blockIdx.y * 64, bn = blockIdx.x * 64;
  ffrag acc[4] = {};
  mg_core(A, B, K, Nn, bm, bn, z * Kslice, (z + 1) * Kslice, As, Bt, acc);
  float* Pz = P + (size_t)z * M * Nn;
  int lane = threadIdx.x & 63, wid = threadIdx.x >> 6;
  int lr = lane & 15, lk = lane >> 4;
  #pragma unroll
  for (int nf = 0; nf < 4; nf++) {
    int col = bn + nf * 16 + lr;
    #pragma unroll
    for (int i = 0; i < 4; i++) {
      int row = bm + wid * 16 + lk * 4 + i;
      Pz[(size_t)row * Nn + col] = acc[nf][i];
    }
  }
}

// bf16 out = gelu(acc + bias)  (W1)
__global__ __launch_bounds__(256) void mgemm_gelu(const unsigned short* __restrict__ A,
    const unsigned short* __restrict__ B, const float* __restrict__ bias,
    unsigned short* __restrict__ C, int M, int Nn, int K) {
  __shared__ __align__(16) unsigned short As[64][40];
  __shared__ __align__(16) unsigned short Bt[64][40];
  int bm = blockIdx.y * 64, bn = blockIdx.x * 64;
  ffrag acc[4] = {};
  mg_core(A, B, K, Nn, bm, bn, 0, K, As, Bt, acc);
  int lane = threadIdx.x & 63, wid = threadIdx.x >> 6;
  int lr = lane & 15, lk = lane >> 4;
  #pragma unroll
  for (int nf = 0; nf < 4; nf++) {
    int col = bn + nf * 16 + lr;
    float bv = bias[col];
    #pragma unroll
    for (int i = 0; i < 4; i++) {
      int row = bm + wid * 16 + lk * 4 + i;
      float v = acc[nf][i] + bv;
      v = 0.5f * v * (1.f + erff(v * 0.70710678118654752f));
      C[(size_t)row * Nn + col] = f2bf(v);
    }
  }
}

// out = sum_s P[s] + bias + R   (final W2 reduce, S=4)  [validated r5]
__global__ __launch_bounds__(256) void reduce_kernel(const float* __restrict__ P,
    const float* __restrict__ bias, const float* __restrict__ R,
    float* __restrict__ out, int MN, int Nn, int S) {
  int i = blockIdx.x * 256 + threadIdx.x;
  if (i * 4 >= MN) return;
  size_t b = (size_t)i * 4;
  float4 acc = *(const float4*)(P + b);
  for (int s = 1; s < S; s++) {
    float4 p = *(const float4*)(P + (size_t)s * MN + b);
    acc.x += p.x; acc.y += p.y; acc.z += p.z; acc.w += p.w;
  }
  float4 bi = *(const float4*)(bias + (b % Nn));
  float4 r  = *(const float4*)(R + b);
  acc.x += bi.x + r.x; acc.y += bi.y + r.y; acc.z += bi.z + r.z; acc.w += bi.w + r.w;
  *(float4*)(out + b) = acc;
}

// ---------------------------------------------------------------- fused Wo-reduce + residual + LayerNorm2  [validated r5]
// x_mid = P0 + P1 + bo + x ; hbf = LN(x_mid) in bf16
__global__ __launch_bounds__(256) void ln2_fused_kernel(const float* __restrict__ P,
    const float* __restrict__ bo, const float* __restrict__ x,
    const float* __restrict__ g, const float* __restrict__ b,
    float* __restrict__ x_mid, unsigned short* __restrict__ hbf, int MN) {
  int row = blockIdx.x;
  int tid = threadIdx.x;
  size_t idx = (size_t)row * D + tid;
  float v = P[idx] + P[(size_t)MN + idx] + bo[tid] + x[idx];
  x_mid[idx] = v;
  float s = v, sq = v * v;
  #pragma unroll
  for (int m = 1; m < 64; m <<= 1) { s += __shfl_xor(s, m); sq += __shfl_xor(sq, m); }
  __shared__ float ps[4], pq[4];
  int wid = tid >> 6, lane = tid & 63;
  if (lane == 0) { ps[wid] = s; pq[wid] = sq; }
  __syncthreads();
  float ts = ps[0] + ps[1] + ps[2] + ps[3];
  float tq = pq[0] + pq[1] + pq[2] + pq[3];
  float mu  = ts * (1.f / D);
  float var = tq * (1.f / D) - mu * mu;
  float inv = 1.f / sqrtf(var + 1e-5f);
  hbf[idx] = f2bf((v - mu) * inv * g[tid] + b[tid]);
}

// ---------------------------------------------------------------- sparse attention with in-wave dedupe  [validated r6]
__global__ __launch_bounds__(256) void attn_kernel(const float* __restrict__ Q,
    const float* __restrict__ Km, const float* __restrict__ Vm,
    const float* __restrict__ eb, const int* __restrict__ cnt,
    const int* __restrict__ colp, const int* __restrict__ eidxp,
    unsigned short* __restrict__ out, int N) {
  int wid = threadIdx.x >> 6, lane = threadIdx.x & 63;
  int n = blockIdx.x * 4 + wid;
  if (n >= N) return;
  int h = lane >> 3, j = lane & 7;
  int off = h * HD + j * 4;
  float4 q = *(const float4*)(Q + (size_t)n * D + off);
  int L = cnt[n];
  if (L > MAXDEG) L = MAXDEG;
  size_t base = (size_t)n * MAXDEG;
  int dv0 = -1, dv1 = -1, dv2 = -1;
  int ev0 = -1, ev1 = -1, ev2 = -1;
  if (lane       < L) { dv0 = colp[base + lane      ]; ev0 = eidxp[base + lane      ]; }
  if (lane +  64 < L) { dv1 = colp[base + lane +  64]; ev1 = eidxp[base + lane +  64]; }
  if (lane + 128 < L) { dv2 = colp[base + lane + 128]; ev2 = eidxp[base + lane + 128]; }
  bool self_present = __any(dv0 == n) || __any(dv1 == n) || __any(dv2 == n);
  float mrun = -INFINITY, srun = 0.f;
  float4 acc = make_float4(0.f, 0.f, 0.f, 0.f);

#define PROC_EDGE(m_, bias_) {                                                 \
    float4 k4 = *(const float4*)(Km + (size_t)(m_) * D + off);                 \
    float dot = q.x * k4.x + q.y * k4.y + q.z * k4.z + q.w * k4.w;             \
    dot += __shfl_xor(dot, 1); dot += __shfl_xor(dot, 2); dot += __shfl_xor(dot, 4); \
    float sc = fmaf(dot, 0.17677669529663687f, bias_);                         \
    float mnew = fmaxf(mrun, sc);                                              \
    float corr = __expf(mrun - mnew);                                          \
    float pp = __expf(sc - mnew);                                              \
    float4 v4 = *(const float4*)(Vm + (size_t)(m_) * D + off);                 \
    srun = srun * corr + pp;                                                   \
    acc.x = fmaf(acc.x, corr, pp * v4.x);                                      \
    acc.y = fmaf(acc.y, corr, pp * v4.y);                                      \
    acc.z = fmaf(acc.z, corr, pp * v4.z);                                      \
    acc.w = fmaf(acc.w, corr, pp * v4.w);                                      \
    mrun = mnew; }

#define PROC_CHUNK(dvC, evC, base_) {                                          \
    int cl = L - (base_); if (cl > 64) cl = 64;                                \
    for (int ii = 0; ii < cl; ii++) {                                          \
      int d_i = __shfl(dvC, ii);                                               \
      int e_i = __shfl(evC, ii);                                               \
      bool dom = (dv0 == d_i && ev0 > e_i) || (dv1 == d_i && ev1 > e_i) ||     \
                 (dv2 == d_i && ev2 > e_i);                                    \
      if (__any(dom)) continue;                                                \
      float bias_ = eb[(size_t)e_i * NH + h];                                  \
      PROC_EDGE(d_i, bias_);                                                   \
    } }

  PROC_CHUNK(dv0, ev0, 0)
  if (L > 64)  PROC_CHUNK(dv1, ev1, 64)
  if (L > 128) PROC_CHUNK(dv2, ev2, 128)
  if (!self_present) PROC_EDGE(n, 0.f)
#undef PROC_CHUNK
#undef PROC_EDGE

  float inv = 1.f / srun;
  ushort4 o = make_ushort4(f2bf(acc.x * inv), f2bf(acc.y * inv),
                           f2bf(acc.z * inv), f2bf(acc.w * inv));
  *(ushort4*)(out + (size_t)n * D + off) = o;
}

// ----------------------------------------------------------------
extern "C" void kernel_launch(void* const* d_in, const int* in_sizes, int n_in,
                              void* d_out, int out_size, void* d_ws, size_t ws_size,
                              hipStream_t stream) {
  const float* x    = (const float*)d_in[0];
  const int*   ei   = (const int*)d_in[1];
  const float* ea   = (const float*)d_in[2];
  const float* Wq   = (const float*)d_in[3];  const float* bq = (const float*)d_in[4];
  const float* Wk   = (const float*)d_in[5];  const float* bk = (const float*)d_in[6];
  const float* Wv   = (const float*)d_in[7];  const float* bv = (const float*)d_in[8];
  const float* Wo   = (const float*)d_in[9];  const float* bo = (const float*)d_in[10];
  const float* We   = (const float*)d_in[11]; const float* be = (const float*)d_in[12];
  const float* W1   = (const float*)d_in[13]; const float* b1 = (const float*)d_in[14];
  const float* W2   = (const float*)d_in[15]; const float* b2 = (const float*)d_in[16];
  const float* ln1g = (const float*)d_in[17]; const float* ln1b = (const float*)d_in[18];
  const float* ln2g = (const float*)d_in[19]; const float* ln2b = (const float*)d_in[20];

  int N = in_sizes[0] / D;
  int E = in_sizes[1] / 2;

  char* p = (char*)d_ws;
  auto alloc = [&](size_t bytes) -> char* {
    char* r = p; p += (bytes + 255) & ~(size_t)255; return r;
  };
  unsigned short* hbf    = (unsigned short*)alloc((size_t)N * D * 2);
  float*          Qd     = (float*)         alloc((size_t)N * D * 4);
  float*          Kd     = (float*)         alloc((size_t)N * D * 4);
  float*          Vd     = (float*)         alloc((size_t)N * D * 4);
  unsigned short* attnbf = (unsigned short*)alloc((size_t)N * D * 2);
  float*          x_mid  = (float*)         alloc((size_t)N * D * 4);
  float*          ebuf   = (float*)         alloc((size_t)E * NH * 4);
  unsigned short* tbf    = (unsigned short*)alloc((size_t)N * 4 * D * 2);
  float*          P      = (float*)         alloc((size_t)4 * N * D * 4);
  unsigned short* Wqb    = (unsigned short*)alloc((size_t)D * D * 2);
  unsigned short* Wkb    = (unsigned short*)alloc((size_t)D * D * 2);
  unsigned short* Wvb    = (unsigned short*)alloc((size_t)D * D * 2);
  unsigned short* Wob    = (unsigned short*)alloc((size_t)D * D * 2);
  unsigned short* W1b    = (unsigned short*)alloc((size_t)D * 4 * D * 2);
  unsigned short* W2b    = (unsigned short*)alloc((size_t)4 * D * D * 2);
  int*            cnt    = (int*)           alloc((size_t)N * 4);
  int*            colp   = (int*)           alloc((size_t)N * MAXDEG * 4);
  int*            eidxp  = (int*)           alloc((size_t)N * MAXDEG * 4);

  hipMemsetAsync(cnt, 0, (size_t)N * 4, stream);

  int MN = N * D;
  int CB = 768;                     // cast blocks (786432/4/256)
  int EB = (E + 255) / 256;

  // prep: cast + LN1 + edge-bias + scatter (one node)
  prep_kernel<<<CB + N + 2 * EB, 256, 0, stream>>>(
      Wq, Wk, Wv, Wo, W1, W2, Wqb, Wkb, Wvb, Wob, W1b, W2b,
      x, ln1g, ln1b, hbf, ei, cnt, colp, eidxp, ea, We, be, ebuf, N, E, CB, EB);
  // QKV (bf16 MFMA)
  dim3 g_qkv(D / 64, N / 64, 3);
  mgemm_qkv<<<g_qkv, 256, 0, stream>>>(hbf, Wqb, Wkb, Wvb, bq, bk, bv,
                                       Qd, Kd, Vd, N, D, D);
  // attention (in-wave dedupe + self-loop) -> bf16
  attn_kernel<<<(N + 3) / 4, 256, 0, stream>>>(Qd, Kd, Vd, ebuf, cnt, colp, eidxp,
                                               attnbf, N);
  // output proj (split-K=2); reduce + residual + LN2 fused
  {
    dim3 g(D / 64, N / 64, 2);
    mgemm_splitk<<<g, 256, 0, stream>>>(attnbf, Wob, P, N, D, D, D / 2);
    ln2_fused_kernel<<<N, 256, 0, stream>>>(P, bo, x, ln2g, ln2b, x_mid, hbf, MN);
  }
  // FFN
  dim3 g_1(4 * D / 64, N / 64);
  mgemm_gelu<<<g_1, 256, 0, stream>>>(hbf, W1b, b1, tbf, N, 4 * D, D);
  // W2 (split-K=4) + bias + residual -> d_out
  {
    dim3 g(D / 64, N / 64, 4);
    mgemm_splitk<<<g, 256, 0, stream>>>(tbf, W2b, P, N, D, 4 * D, D);
    reduce_kernel<<<(MN / 4 + 255) / 256, 256, 0, stream>>>(P, b2, x_mid, (float*)d_out,
                                                            MN, D, 4);
  }
}